// Round 9
// baseline (1105.733 us; speedup 1.0000x reference)
//
#include <hip/hip_runtime.h>
#include <hip/hip_bf16.h>
#include <math.h>

typedef short short8v __attribute__((ext_vector_type(8)));
typedef float f32x4 __attribute__((ext_vector_type(4)));
typedef unsigned short ushort4v __attribute__((ext_vector_type(4)));

__device__ inline float waveReduceSum(float v){
  #pragma unroll
  for (int off = 32; off > 0; off >>= 1) v += __shfl_xor(v, off, 64);
  return v;
}

// bf16 helpers (manual RNE)
__device__ inline unsigned short f2bf(float x){
  unsigned int u = __builtin_bit_cast(unsigned int, x);
  unsigned int r = (u + 0x7FFFu + ((u >> 16) & 1u)) >> 16;
  return (unsigned short)r;
}
__device__ inline float bf2f(unsigned short u){
  unsigned int w = ((unsigned int)u) << 16;
  return __builtin_bit_cast(float, w);
}

#define TCN_O_OFF 139264   // o tile after 544-row h tile

// ============================================================================
// init: TCN weight fragments (split hi/lo, MFMA A-layout) + PE table
// ============================================================================
__global__ void init_kernel(const float* __restrict__ w1, const float* __restrict__ w2,
                            unsigned short* __restrict__ wf, float* __restrict__ petab){
  int idx = blockIdx.x * 256 + threadIdx.x;
  if (idx < 98304){
    int conv = idx / 12288;
    int r = idx % 12288;
    int tap = r >> 12;
    int kk  = (r >> 11) & 1;
    int ct  = (r >> 9) & 3;
    int lane= (r >> 3) & 63;
    int j   = r & 7;
    int layer = conv >> 1;
    const float* src = (conv & 1) ? w2 : w1;
    int co = (ct << 4) + (lane & 15);
    int ci = (kk << 5) + ((lane >> 4) << 3) + j;
    float v = src[((layer * 64 + co) * 64 + ci) * 3 + tap];
    unsigned short hi = f2bf(v);
    unsigned short lo = f2bf(v - bf2f(hi));
    size_t base = (size_t)conv * 24576 + (size_t)(((tap * 2 + kk) * 4 + ct) * 2) * 512 + lane * 8 + j;
    wf[base] = hi;
    wf[base + 512] = lo;
  } else if (idx < 131072){
    int p = idx - 98304;
    int t = p >> 6, c = p & 63;
    float ang = (float)t * expf(-0.14391156831f * (float)(c & ~1));
    petab[p] = (c & 1) ? cosf(ang) : sinf(ang);
  }
}

// ============================================================================
// One TCN layer (constexpr DIL/CONVBASE -> foldable addressing, no spills).
// 16 waves: coq (0..3) = 16-co tile, tsub (0..3) = 16-t subtile.
// ============================================================================
template<int LAYER>
__device__ __forceinline__ void run_layer(
    char* lds, const unsigned short* __restrict__ wfrag,
    const float* __restrict__ b1g, const float* __restrict__ b2g,
    int lane, int coq, int tsub){
  constexpr int DIL = 1 << LAYER;
  constexpr int CONVBASE = LAYER * 2;
  const int cobase = (coq << 4) + ((lane >> 4) << 2);
  const f32x4 b1v = *(const f32x4*)(b1g + (LAYER << 6) + cobase);
  const f32x4 b2v = *(const f32x4*)(b2g + (LAYER << 6) + cobase);

  for (int ch = 7; ch >= 0; --ch){
    const int t0 = ch << 6;
    __syncthreads();   // h stable from previous chunk/layer; o buffer free

    // ---- A fragments for conv1: 12 short8v (48 VGPR) ----
    short8v A1[3][2][2];
    #pragma unroll
    for (int tap = 0; tap < 3; ++tap)
      #pragma unroll
      for (int kk = 0; kk < 2; ++kk)
        #pragma unroll
        for (int pl = 0; pl < 2; ++pl)
          A1[tap][kk][pl] = *(const short8v*)(wfrag + (size_t)CONVBASE * 24576 +
              (size_t)((((tap * 2 + kk) * 4 + coq) * 2 + pl)) * 512 + lane * 8);

    // ---- conv1: o rows 0..79 (t = t0-16+orow) ----
    #pragma unroll
    for (int S = 0; S < 2; ++S){
      int rbase = (S << 6) + (tsub << 4);
      if (rbase < 80){                       // wave-uniform
        f32x4 acc = {0.f,0.f,0.f,0.f};
        int orow = rbase + (lane & 15);
        int t_o = t0 - 16 + orow;
        #pragma unroll
        for (int tap = 0; tap < 3; ++tap){
          int hr = t_o - (2 - tap) * DIL + 32;   // >= 0 (32 zero rows)
          int sw = (hr & 7) << 4;
          #pragma unroll
          for (int kk = 0; kk < 2; ++kk){
            int base = (hr << 8) + (kk << 6) + ((lane >> 4) << 4);
            short8v Bhi = *(const short8v*)(lds + (base ^ sw));
            short8v Blo = *(const short8v*)(lds + ((base + 128) ^ sw));
            acc = __builtin_amdgcn_mfma_f32_16x16x32_bf16(A1[tap][kk][0], Bhi, acc, 0, 0, 0);
            acc = __builtin_amdgcn_mfma_f32_16x16x32_bf16(A1[tap][kk][0], Blo, acc, 0, 0, 0);
            acc = __builtin_amdgcn_mfma_f32_16x16x32_bf16(A1[tap][kk][1], Bhi, acc, 0, 0, 0);
          }
        }
        int swO = (orow & 7) << 4;
        ushort4v hi4, lo4;
        #pragma unroll
        for (int r = 0; r < 4; ++r){
          float v = fmaxf(acc[r] + b1v[r], 0.f);
          if (t_o < 0) v = 0.f;
          unsigned short h = f2bf(v);
          hi4[r] = h;
          lo4[r] = f2bf(v - bf2f(h));
        }
        int ob = TCN_O_OFF + (orow << 8) + (cobase << 1);
        *(ushort4v*)(lds + (ob ^ swO)) = hi4;
        *(ushort4v*)(lds + ((ob + 128) ^ swO)) = lo4;
      }
    }

    // ---- A fragments for conv2 (issued before barrier to overlap) ----
    short8v A2[3][2][2];
    #pragma unroll
    for (int tap = 0; tap < 3; ++tap)
      #pragma unroll
      for (int kk = 0; kk < 2; ++kk)
        #pragma unroll
        for (int pl = 0; pl < 2; ++pl)
          A2[tap][kk][pl] = *(const short8v*)(wfrag + (size_t)(CONVBASE + 1) * 24576 +
              (size_t)((((tap * 2 + kk) * 4 + coq) * 2 + pl)) * 512 + lane * 8);
    __syncthreads();   // o writes visible

    // ---- conv2: outputs t0..t0+63 (16 waves, one tile each) ----
    {
      f32x4 acc = {0.f,0.f,0.f,0.f};
      int tt = (tsub << 4) + (lane & 15);
      #pragma unroll
      for (int tap = 0; tap < 3; ++tap){
        int ol = tt + 16 - (2 - tap) * DIL;   // local o row 0..79
        int sw = (ol & 7) << 4;
        #pragma unroll
        for (int kk = 0; kk < 2; ++kk){
          int base = TCN_O_OFF + (ol << 8) + (kk << 6) + ((lane >> 4) << 4);
          short8v Bhi = *(const short8v*)(lds + (base ^ sw));
          short8v Blo = *(const short8v*)(lds + ((base + 128) ^ sw));
          acc = __builtin_amdgcn_mfma_f32_16x16x32_bf16(A2[tap][kk][0], Bhi, acc, 0, 0, 0);
          acc = __builtin_amdgcn_mfma_f32_16x16x32_bf16(A2[tap][kk][0], Blo, acc, 0, 0, 0);
          acc = __builtin_amdgcn_mfma_f32_16x16x32_bf16(A2[tap][kk][1], Bhi, acc, 0, 0, 0);
        }
      }
      // h' = relu(relu(acc+b2) + h_old), in place (lane reads+writes own addr)
      int hr = t0 + tt + 32;
      int swH = (hr & 7) << 4;
      int rb = (hr << 8) + (cobase << 1);
      ushort4v rhi = *(const ushort4v*)(lds + (rb ^ swH));
      ushort4v rlo = *(const ushort4v*)(lds + ((rb + 128) ^ swH));
      ushort4v hi4, lo4;
      #pragma unroll
      for (int r = 0; r < 4; ++r){
        float v = fmaxf(acc[r] + b2v[r], 0.f);
        v = fmaxf(v + bf2f(rhi[r]) + bf2f(rlo[r]), 0.f);
        unsigned short h = f2bf(v);
        hi4[r] = h;
        lo4[r] = f2bf(v - bf2f(h));
      }
      *(ushort4v*)(lds + (rb ^ swH)) = hi4;
      *(ushort4v*)(lds + ((rb + 128) ^ swH)) = lo4;
    }
  }
}

// ============================================================================
// Persistent per-sequence TCN: proj+PE -> 4 layers (all in LDS) -> LN+pool.
// 1024 blocks x 1024 threads (16 waves). LDS: h 544x256 + o 80x256 = 159744 B.
// Reverse chunk order makes in-place h overwrite safe (causal convs).
// ============================================================================
__global__ __launch_bounds__(1024, 4) void tcn_persist_kernel(
    const float* __restrict__ x, const unsigned short* __restrict__ wfrag,
    const float* __restrict__ b1g, const float* __restrict__ b2g,
    const float* __restrict__ petab,
    const float* __restrict__ pw, const float* __restrict__ pb,
    const float* __restrict__ lng, const float* __restrict__ lnb,
    const float* __restrict__ maskg,
    float* __restrict__ pooled, float* __restrict__ stlast){
  __shared__ __align__(16) char lds[159744];
  const int tid = threadIdx.x;
  const int lane = tid & 63, wid = tid >> 6;   // 16 waves
  const int coq = wid & 3, tsub = wid >> 2;
  const int bn = blockIdx.x;
  const int bb = bn >> 5, nn = bn & 31;

  // ---- stage proj + PE into h rows 0..543 (t = row-32; zeros for t<0) ----
  #pragma unroll
  for (int i = 0; i < 5; ++i){
    int idx = tid + i * 1024;
    if (idx < 4352){
      int row = idx >> 3, cg = idx & 7;
      int t = row - 32;
      short8v vh = {0,0,0,0,0,0,0,0}, vl = {0,0,0,0,0,0,0,0};
      if (t >= 0){
        float xv = x[((size_t)bb << 14) + (t << 5) + nn];
        const float* per = petab + t * 64 + cg * 8;
        #pragma unroll
        for (int j = 0; j < 8; ++j){
          int c = cg * 8 + j;
          float val = fmaf(xv, pw[c], pb[c]) + per[j];
          unsigned short h = f2bf(val);
          vh[j] = (short)h;
          vl[j] = (short)f2bf(val - bf2f(h));
        }
      }
      int sw = (row & 7) << 4;
      int base = (row << 8) + (cg << 4);
      *(short8v*)(lds + (base ^ sw)) = vh;
      *(short8v*)(lds + ((base + 128) ^ sw)) = vl;
    }
  }

  run_layer<0>(lds, wfrag, b1g, b2g, lane, coq, tsub);
  run_layer<1>(lds, wfrag, b1g, b2g, lane, coq, tsub);
  run_layer<2>(lds, wfrag, b1g, b2g, lane, coq, tsub);
  run_layer<3>(lds, wfrag, b1g, b2g, lane, coq, tsub);

  __syncthreads();
  // ---- LN over channels + masked mean-pool + st_last ----
  {
    int s8 = tid >> 6, c = tid & 63;           // 16 groups x 32 rows
    float gc = lng[c], bc = lnb[c];
    float mk = maskg[bn];
    float acc = 0.f;
    for (int r0 = 0; r0 < 32; ++r0){
      int row = (s8 << 5) + r0;                // 0..511
      int hr = row + 32;
      int sw = (hr & 7) << 4;
      int base = (hr << 8) + (c << 1);
      float hi = bf2f(*(const unsigned short*)(lds + (base ^ sw)));
      float lo = bf2f(*(const unsigned short*)(lds + ((base + 128) ^ sw)));
      float val = hi + lo;
      float sum = val, sq = val * val;
      #pragma unroll
      for (int off = 32; off > 0; off >>= 1){
        sum += __shfl_xor(sum, off, 64);
        sq  += __shfl_xor(sq, off, 64);
      }
      float mean = sum * (1.f / 64.f);
      float var = sq * (1.f / 64.f) - mean * mean;
      float rstd = rsqrtf(var + 1e-5f);
      float o = (val - mean) * rstd * gc + bc;
      acc += o;
      if (row == 511) stlast[(size_t)bn * 64 + c] = o * mk;
    }
    __syncthreads();   // all h reads done; o-tile region reusable for partials
    *(float*)(lds + TCN_O_OFF + ((s8 << 6) + c) * 4) = acc;
    __syncthreads();
    if (tid < 64){
      float tot = 0.f;
      #pragma unroll
      for (int ss = 0; ss < 16; ++ss) tot += *(const float*)(lds + TCN_O_OFF + ((ss << 6) + tid) * 4);
      pooled[(size_t)bn * 64 + tid] = tot * (1.f / 512.f) * mk;
    }
  }
}

// ============================================================================
// Fused per-batch tail, 32 blocks x 1024 threads.
// ============================================================================
__global__ __launch_bounds__(1024) void batch_kernel(
    const float* __restrict__ pooled, const float* __restrict__ maskg,
    const float* __restrict__ pool_w, const float* __restrict__ pool_b,
    const float* __restrict__ pos,
    const float* __restrict__ ln1g, const float* __restrict__ ln1b,
    const float* __restrict__ qkvw, const float* __restrict__ qkvb_g,
    const float* __restrict__ outw, const float* __restrict__ outb,
    const float* __restrict__ ln2g, const float* __restrict__ ln2b,
    const float* __restrict__ ff1w, const float* __restrict__ ff1b,
    const float* __restrict__ ff2w, const float* __restrict__ ff2b,
    const float* __restrict__ flng, const float* __restrict__ flnb,
    const float* __restrict__ ew1, const float* __restrict__ eb1,
    const float* __restrict__ ew2, const float* __restrict__ eb2,
    const float* __restrict__ gfw, const float* __restrict__ gfb,
    const float* __restrict__ gfailw, const float* __restrict__ gfailb,
    const float* __restrict__ failw, const float* __restrict__ failb,
    float* __restrict__ ctxg, float* __restrict__ moefg,
    float* __restrict__ logitsfg, int* __restrict__ tifg,
    float* __restrict__ outg){
  __shared__ float zf[32][128];
  __shared__ float ybuf[32][128];
  __shared__ float qkvb[32][385];
  __shared__ float sc[8][33][33];
  __shared__ float ps[32][64];
  __shared__ float msk[32];
  __shared__ float rin[256];
  __shared__ float meanc[128];
  __shared__ float h1all[4][256];
  __shared__ float oall[4][128];
  __shared__ float lf[16], lfail[16];
  __shared__ int   tisel[4];
  __shared__ float twsel[4];
  __shared__ float moefail[128];
  __shared__ float cntS;

  const int b = blockIdx.x;
  const int tid = threadIdx.x;
  const int lane = tid & 63;

  if (tid < 32) msk[tid] = maskg[b * 32 + tid];
  #pragma unroll
  for (int i = 0; i < 2; ++i){
    int item = tid + 1024 * i;
    int n = item >> 6, c = item & 63;
    ps[n][c] = pooled[(size_t)(b * 32 + n) * 64 + c];
  }
  __syncthreads();

  // z init
  {
    int jb = tid & 63, nb = tid >> 6;
    float acc[2][2];
    #pragma unroll
    for (int nn = 0; nn < 2; ++nn)
      #pragma unroll
      for (int jj = 0; jj < 2; ++jj){
        int d = jb * 2 + jj, n = nb * 2 + nn;
        acc[nn][jj] = pool_b[d] + pos[n * 128 + d];
      }
    #pragma unroll 8
    for (int k = 0; k < 64; ++k){
      float w0 = pool_w[k * 128 + jb * 2], w1 = pool_w[k * 128 + jb * 2 + 1];
      #pragma unroll
      for (int nn = 0; nn < 2; ++nn){
        float y = ps[nb * 2 + nn][k];
        acc[nn][0] += y * w0; acc[nn][1] += y * w1;
      }
    }
    #pragma unroll
    for (int nn = 0; nn < 2; ++nn){
      zf[nb * 2 + nn][jb * 2]     = acc[nn][0];
      zf[nb * 2 + nn][jb * 2 + 1] = acc[nn][1];
    }
  }
  __syncthreads();

  for (int l = 0; l < 2; ++l){
    const float* Wq = qkvw + (size_t)l * 49152;
    const float* bq = qkvb_g + l * 384;
    const float* Wo = outw + (size_t)l * 16384;
    const float* bo = outb + l * 128;
    const float* W1 = ff1w + (size_t)l * 32768;
    const float* bf1 = ff1b + l * 256;
    const float* W2 = ff2w + (size_t)l * 32768;
    const float* bf2 = ff2b + l * 128;
    const float* g1 = ln1g + l * 128; const float* bb1 = ln1b + l * 128;
    const float* g2 = ln2g + l * 128; const float* bb2 = ln2b + l * 128;

    // LN1
    #pragma unroll
    for (int rr = 0; rr < 2; ++rr){
      int row = (tid >> 6) * 2 + rr;
      float x0 = zf[row][lane], x1 = zf[row][lane + 64];
      float mean = waveReduceSum(x0 + x1) * (1.f / 128.f);
      float d0 = x0 - mean, d1 = x1 - mean;
      float var = waveReduceSum(d0 * d0 + d1 * d1) * (1.f / 128.f);
      float rstd = rsqrtf(var + 1e-5f);
      ybuf[row][lane]      = d0 * rstd * g1[lane] + bb1[lane];
      ybuf[row][lane + 64] = d1 * rstd * g1[lane + 64] + bb1[lane + 64];
    }
    __syncthreads();

    // qkv
    {
      int jb = tid & 127, nb = tid >> 7;
      float acc[4][3];
      #pragma unroll
      for (int nn = 0; nn < 4; ++nn)
        #pragma unroll
        for (int jj = 0; jj < 3; ++jj) acc[nn][jj] = 0.f;
      #pragma unroll 8
      for (int k = 0; k < 128; ++k){
        float w0 = Wq[k * 384 + jb * 3], w1 = Wq[k * 384 + jb * 3 + 1], w2v = Wq[k * 384 + jb * 3 + 2];
        #pragma unroll
        for (int nn = 0; nn < 4; ++nn){
          float y = ybuf[nb * 4 + nn][k];
          acc[nn][0] += y * w0; acc[nn][1] += y * w1; acc[nn][2] += y * w2v;
        }
      }
      #pragma unroll
      for (int nn = 0; nn < 4; ++nn)
        #pragma unroll
        for (int jj = 0; jj < 3; ++jj)
          qkvb[nb * 4 + nn][jb * 3 + jj] = acc[nn][jj] + bq[jb * 3 + jj];
    }
    __syncthreads();

    // scores
    #pragma unroll
    for (int i = 0; i < 8; ++i){
      int item = tid + 1024 * i;
      int hh = item >> 10, qi = (item >> 5) & 31, ki = item & 31;
      float a = 0.f;
      #pragma unroll
      for (int d = 0; d < 16; ++d) a += qkvb[qi][hh * 16 + d] * qkvb[ki][128 + hh * 16 + d];
      a *= 0.25f;
      if (msk[ki] == 0.f) a = -1e9f;
      sc[hh][qi][ki] = a;
    }
    __syncthreads();
    // softmax
    {
      int row = tid >> 2, q4 = tid & 3;
      int hh = row >> 5, qi = row & 31;
      float v[8];
      float m = -1e30f;
      #pragma unroll
      for (int j = 0; j < 8; ++j){ v[j] = sc[hh][qi][q4 * 8 + j]; m = fmaxf(m, v[j]); }
      m = fmaxf(m, __shfl_xor(m, 1, 64));
      m = fmaxf(m, __shfl_xor(m, 2, 64));
      float s = 0.f;
      #pragma unroll
      for (int j = 0; j < 8; ++j){ v[j] = expf(v[j] - m); s += v[j]; }
      s += __shfl_xor(s, 1, 64);
      s += __shfl_xor(s, 2, 64);
      float inv = 1.f / s;
      #pragma unroll
      for (int j = 0; j < 8; ++j) sc[hh][qi][q4 * 8 + j] = v[j] * inv;
    }
    __syncthreads();
    // o -> ybuf
    #pragma unroll
    for (int i = 0; i < 4; ++i){
      int item = tid + 1024 * i;
      int n = item >> 7, dd = item & 127, hh = dd >> 4;
      float o = 0.f;
      #pragma unroll
      for (int ki = 0; ki < 32; ++ki) o += sc[hh][n][ki] * qkvb[ki][256 + dd];
      ybuf[n][dd] = o;
    }
    __syncthreads();

    // z += o @ Wo + bo
    {
      int jb = tid & 63, nb = tid >> 6;
      float acc[2][2];
      #pragma unroll
      for (int nn = 0; nn < 2; ++nn){ acc[nn][0] = 0.f; acc[nn][1] = 0.f; }
      #pragma unroll 8
      for (int k = 0; k < 128; ++k){
        float w0 = Wo[k * 128 + jb * 2], w1 = Wo[k * 128 + jb * 2 + 1];
        #pragma unroll
        for (int nn = 0; nn < 2; ++nn){
          float y = ybuf[nb * 2 + nn][k];
          acc[nn][0] += y * w0; acc[nn][1] += y * w1;
        }
      }
      #pragma unroll
      for (int nn = 0; nn < 2; ++nn){
        zf[nb * 2 + nn][jb * 2]     += acc[nn][0] + bo[jb * 2];
        zf[nb * 2 + nn][jb * 2 + 1] += acc[nn][1] + bo[jb * 2 + 1];
      }
    }
    __syncthreads();

    // LN2
    #pragma unroll
    for (int rr = 0; rr < 2; ++rr){
      int row = (tid >> 6) * 2 + rr;
      float x0 = zf[row][lane], x1 = zf[row][lane + 64];
      float mean = waveReduceSum(x0 + x1) * (1.f / 128.f);
      float d0 = x0 - mean, d1 = x1 - mean;
      float var = waveReduceSum(d0 * d0 + d1 * d1) * (1.f / 128.f);
      float rstd = rsqrtf(var + 1e-5f);
      ybuf[row][lane]      = d0 * rstd * g2[lane] + bb2[lane];
      ybuf[row][lane + 64] = d1 * rstd * g2[lane + 64] + bb2[lane + 64];
    }
    __syncthreads();

    // ff1
    {
      int jb = tid & 127, nb = tid >> 7;
      float acc[4][2];
      #pragma unroll
      for (int nn = 0; nn < 4; ++nn){ acc[nn][0] = 0.f; acc[nn][1] = 0.f; }
      #pragma unroll 8
      for (int k = 0; k < 128; ++k){
        float w0 = W1[k * 256 + jb * 2], w1 = W1[k * 256 + jb * 2 + 1];
        #pragma unroll
        for (int nn = 0; nn < 4; ++nn){
          float y = ybuf[nb * 4 + nn][k];
          acc[nn][0] += y * w0; acc[nn][1] += y * w1;
        }
      }
      #pragma unroll
      for (int nn = 0; nn < 4; ++nn){
        qkvb[nb * 4 + nn][jb * 2]     = fmaxf(acc[nn][0] + bf1[jb * 2], 0.f);
        qkvb[nb * 4 + nn][jb * 2 + 1] = fmaxf(acc[nn][1] + bf1[jb * 2 + 1], 0.f);
      }
    }
    __syncthreads();

    // z += ff @ W2 + bf2
    {
      int jb = tid & 63, nb = tid >> 6;
      float acc[2][2];
      #pragma unroll
      for (int nn = 0; nn < 2; ++nn){ acc[nn][0] = 0.f; acc[nn][1] = 0.f; }
      #pragma unroll 8
      for (int k = 0; k < 256; ++k){
        float w0 = W2[k * 128 + jb * 2], w1 = W2[k * 128 + jb * 2 + 1];
        #pragma unroll
        for (int nn = 0; nn < 2; ++nn){
          float y = qkvb[nb * 2 + nn][k];
          acc[nn][0] += y * w0; acc[nn][1] += y * w1;
        }
      }
      #pragma unroll
      for (int nn = 0; nn < 2; ++nn){
        zf[nb * 2 + nn][jb * 2]     += acc[nn][0] + bf2[jb * 2];
        zf[nb * 2 + nn][jb * 2 + 1] += acc[nn][1] + bf2[jb * 2 + 1];
      }
    }
    __syncthreads();
  }

  // final LN * mask -> ybuf + ctx
  #pragma unroll
  for (int rr = 0; rr < 2; ++rr){
    int row = (tid >> 6) * 2 + rr;
    float x0 = zf[row][lane], x1 = zf[row][lane + 64];
    float mean = waveReduceSum(x0 + x1) * (1.f / 128.f);
    float d0 = x0 - mean, d1 = x1 - mean;
    float var = waveReduceSum(d0 * d0 + d1 * d1) * (1.f / 128.f);
    float rstd = rsqrtf(var + 1e-5f);
    float mk = msk[row];
    ybuf[row][lane]      = (d0 * rstd * flng[lane] + flnb[lane]) * mk;
    ybuf[row][lane + 64] = (d1 * rstd * flng[lane + 64] + flnb[lane + 64]) * mk;
  }
  if (tid == 0){
    float c = 0.f;
    for (int n = 0; n < 32; ++n) c += maskg[b * 32 + n];
    cntS = fmaxf(c, 1.f);
  }
  __syncthreads();
  #pragma unroll
  for (int i = 0; i < 4; ++i){
    int item = tid + 1024 * i;
    int n = item >> 7, d = item & 127;
    ctxg[(size_t)(b * 32 + n) * 128 + d] = ybuf[n][d];
  }
  if (tid < 128){
    float s = 0.f, s2 = 0.f;
    #pragma unroll 8
    for (int n = 0; n < 32; ++n){ float v = ybuf[n][tid]; s += v; s2 += v * v; }
    float mean = s / cntS;
    float var = s2 / cntS - mean * mean;
    meanc[tid] = mean;
    rin[tid] = mean;
    rin[128 + tid] = sqrtf(fmaxf(var, 1e-6f));
  }
  __syncthreads();
  // gates
  {
    int g = tid >> 9;
    int e = (tid >> 5) & 15, kk = tid & 31;
    const float* gw = g ? gfailw : gfw;
    float a = 0.f;
    #pragma unroll
    for (int j = 0; j < 8; ++j){
      int k = kk * 8 + j;
      a += rin[k] * gw[k * 16 + e];
    }
    a += __shfl_xor(a, 1, 64);  a += __shfl_xor(a, 2, 64);
    a += __shfl_xor(a, 4, 64);  a += __shfl_xor(a, 8, 64);
    a += __shfl_xor(a, 16, 64);
    if (kk == 0){
      if (g == 0){
        float r = a + gfb[e];
        lf[e] = r;
        logitsfg[b * 16 + e] = r;
      } else {
        lfail[e] = a + gfailb[e];
      }
    }
  }
  __syncthreads();
  if (tid < 2){
    const float* lg = (tid == 0) ? lf : lfail;
    int i0 = 0; float v0 = lg[0];
    for (int e = 1; e < 16; ++e) if (lg[e] > v0){ v0 = lg[e]; i0 = e; }
    int i1 = -1; float v1 = -1e30f;
    for (int e = 0; e < 16; ++e) if (e != i0 && lg[e] > v1){ v1 = lg[e]; i1 = e; }
    float e1 = expf(v1 - v0);
    float den = 1.f / (1.f + e1);
    tisel[tid * 2] = i0; tisel[tid * 2 + 1] = i1;
    twsel[tid * 2] = den; twsel[tid * 2 + 1] = e1 * den;
    if (tid == 0){ tifg[b * 2] = i0; tifg[b * 2 + 1] = i1; }
  }
  __syncthreads();
  // MoE: 4 selected experts in parallel
  {
    int sel = tid >> 8, h = tid & 255;
    int e = tisel[sel];
    float a = eb1[e * 256 + h];
    #pragma unroll 8
    for (int k = 0; k < 128; ++k) a += meanc[k] * ew1[(size_t)(e * 128 + k) * 256 + h];
    h1all[sel][h] = fmaxf(a, 0.f);
  }
  __syncthreads();
  if (tid < 512){
    int sel = tid >> 7, d = tid & 127;
    int e = tisel[sel];
    float o = eb2[e * 128 + d];
    #pragma unroll 8
    for (int k = 0; k < 256; ++k) o += h1all[sel][k] * ew2[(size_t)(e * 256 + k) * 128 + d];
    oall[sel][d] = twsel[sel] * o;
  }
  __syncthreads();
  if (tid < 128){
    moefg[b * 128 + tid] = oall[0][tid] + oall[1][tid];
    moefail[tid] = oall[2][tid] + oall[3][tid];
  }
  __syncthreads();
  if (tid < 3){
    float a = failb[tid];
    for (int k = 0; k < 128; ++k) a += moefail[k] * failw[k * 3 + tid];
    outg[3072 + b * 3 + tid] = a;
  }
}

// ---------------- gate (rca) ----------------
__global__ void gate_kernel(const float* __restrict__ gin, const float* __restrict__ gw,
                            const float* __restrict__ gb, int ntok, int K,
                            int* __restrict__ ti, float* __restrict__ tw,
                            float* __restrict__ logits_out){
  int tok = blockIdx.x * 64 + threadIdx.x;
  if (tok >= ntok) return;
  float acc[16];
  #pragma unroll
  for (int e = 0; e < 16; ++e) acc[e] = gb[e];
  const float* gr = gin + (size_t)tok * K;
  #pragma unroll 4
  for (int k = 0; k < K; ++k){
    float gv = gr[k];
    #pragma unroll
    for (int e = 0; e < 16; ++e) acc[e] = fmaf(gv, gw[k*16 + e], acc[e]);
  }
  if (logits_out){
    #pragma unroll
    for (int e = 0; e < 16; ++e) logits_out[tok*16 + e] = acc[e];
  }
  int i0 = 0; float v0 = acc[0];
  #pragma unroll
  for (int e = 1; e < 16; ++e) if (acc[e] > v0){ v0 = acc[e]; i0 = e; }
  int i1 = -1; float v1 = -1e30f;
  #pragma unroll
  for (int e = 0; e < 16; ++e) if (e != i0 && acc[e] > v1){ v1 = acc[e]; i1 = e; }
  float e1 = expf(v1 - v0);
  float den = 1.f / (1.f + e1);
  ti[tok*2] = i0; ti[tok*2+1] = i1;
  tw[tok*2] = den; tw[tok*2+1] = e1 * den;
}

// ---------------- MoE expert eval (rca) ----------------
__global__ void moe_expert_kernel(const float* __restrict__ xin, const int* __restrict__ ti,
                                  const float* __restrict__ tw,
                                  const float* __restrict__ w1, const float* __restrict__ b1,
                                  const float* __restrict__ w2, const float* __restrict__ b2,
                                  const float* __restrict__ mask, float* __restrict__ yout){
  int tok = blockIdx.x;
  int tid = threadIdx.x; // 256
  __shared__ float xs[128];
  __shared__ float h1[256];
  if (tid < 128) xs[tid] = xin[(size_t)tok*128 + tid];
  __syncthreads();
  float accv = 0.f;
  for (int kkk = 0; kkk < 2; ++kkk){
    int e = ti[tok*2 + kkk];
    float wv = tw[tok*2 + kkk];
    float a = b1[e*256 + tid];
    #pragma unroll 8
    for (int k = 0; k < 128; ++k) a = fmaf(xs[k], w1[(size_t)(e*128 + k)*256 + tid], a);
    __syncthreads();
    h1[tid] = fmaxf(a, 0.f);
    __syncthreads();
    if (tid < 128){
      float o = b2[e*128 + tid];
      #pragma unroll 8
      for (int k = 0; k < 256; ++k) o = fmaf(h1[k], w2[(size_t)(e*256 + k)*128 + tid], o);
      accv += wv * o;
    }
  }
  if (tid < 128){
    if (mask) accv *= mask[tok];
    yout[(size_t)tok*128 + tid] = accv;
  }
}

// ---------------- aux loss ----------------
__global__ void aux_kernel(const float* __restrict__ logits, const int* __restrict__ ti,
                           float* __restrict__ out_scalar){
  if (threadIdx.x != 0 || blockIdx.x != 0) return;
  float pm[16];
  for (int e = 0; e < 16; ++e) pm[e] = 0.f;
  for (int i = 0; i < 32; ++i){
    const float* row = logits + i*16;
    float m = -1e30f;
    for (int e = 0; e < 16; ++e) m = fmaxf(m, row[e]);
    float s = 0.f;
    float ex[16];
    for (int e = 0; e < 16; ++e){ ex[e] = expf(row[e] - m); s += ex[e]; }
    for (int e = 0; e < 16; ++e) pm[e] += ex[e] / s;
  }
  float cnt[16];
  for (int e = 0; e < 16; ++e) cnt[e] = 0.f;
  for (int i = 0; i < 64; ++i) cnt[ti[i]] += 1.f;
  float loss = 0.f;
  for (int e = 0; e < 16; ++e) loss += (pm[e] / 32.f) * (cnt[e] / 64.f);
  out_scalar[0] = 16.f * loss;
}

// ---------------- pred + rca heads ----------------
__global__ void heads_kernel(const float* __restrict__ st_last, const float* __restrict__ ctx,
                             const float* __restrict__ moe_f, const float* __restrict__ moe_rca,
                             const float* __restrict__ pred_w, const float* __restrict__ pred_b,
                             const float* __restrict__ rca_w, const float* __restrict__ rca_b,
                             float* __restrict__ out){
  int bn = blockIdx.x * 256 + threadIdx.x;
  if (bn >= 1024) return;
  int b = bn >> 5;
  float p0 = pred_b[0], p1 = pred_b[1], p2 = pred_b[2];
  float r = rca_b[0];
  #pragma unroll 4
  for (int i = 0; i < 64; ++i){
    float v = st_last[(size_t)bn*64 + i];
    p0 = fmaf(v, pred_w[i*3+0], p0); p1 = fmaf(v, pred_w[i*3+1], p1); p2 = fmaf(v, pred_w[i*3+2], p2);
    r = fmaf(v, rca_w[i], r);
  }
  #pragma unroll 4
  for (int i = 0; i < 128; ++i){
    float v = ctx[(size_t)bn*128 + i];
    int ii = 64 + i;
    p0 = fmaf(v, pred_w[ii*3+0], p0); p1 = fmaf(v, pred_w[ii*3+1], p1); p2 = fmaf(v, pred_w[ii*3+2], p2);
    r = fmaf(v, rca_w[ii], r);
  }
  #pragma unroll 4
  for (int i = 0; i < 128; ++i){
    int ii = 192 + i;
    float vp = moe_f[(size_t)b*128 + i];
    p0 = fmaf(vp, pred_w[ii*3+0], p0); p1 = fmaf(vp, pred_w[ii*3+1], p1); p2 = fmaf(vp, pred_w[ii*3+2], p2);
    float vr = moe_rca[(size_t)bn*128 + i];
    r = fmaf(vr, rca_w[ii], r);
  }
  out[bn*3+0] = p0; out[bn*3+1] = p1; out[bn*3+2] = p2;
  out[3168 + bn] = r;
}

// ================= host =================
extern "C" void kernel_launch(void* const* d_in, const int* in_sizes, int n_in,
                              void* d_out, int out_size, void* d_ws, size_t ws_size,
                              hipStream_t stream){
  const float* x        = (const float*)d_in[0];
  const float* mask     = (const float*)d_in[1];
  const float* proj_w   = (const float*)d_in[2];
  const float* proj_b   = (const float*)d_in[3];
  const float* tcn_w1   = (const float*)d_in[4];
  const float* tcn_b1   = (const float*)d_in[5];
  const float* tcn_w2   = (const float*)d_in[6];
  const float* tcn_b2   = (const float*)d_in[7];
  const float* tcn_ln_g = (const float*)d_in[8];
  const float* tcn_ln_b = (const float*)d_in[9];
  const float* pool_w   = (const float*)d_in[10];
  const float* pool_b   = (const float*)d_in[11];
  const float* pos_inter= (const float*)d_in[12];
  const float* tx_ln1_g = (const float*)d_in[13];
  const float* tx_ln1_b = (const float*)d_in[14];
  const float* tx_qkv_w = (const float*)d_in[15];
  const float* tx_qkv_b = (const float*)d_in[16];
  const float* tx_out_w = (const float*)d_in[17];
  const float* tx_out_b = (const float*)d_in[18];
  const float* tx_ln2_g = (const float*)d_in[19];
  const float* tx_ln2_b = (const float*)d_in[20];
  const float* tx_ff1_w = (const float*)d_in[21];
  const float* tx_ff1_b = (const float*)d_in[22];
  const float* tx_ff2_w = (const float*)d_in[23];
  const float* tx_ff2_b = (const float*)d_in[24];
  const float* tx_fln_g = (const float*)d_in[25];
  const float* tx_fln_b = (const float*)d_in[26];
  const float* exp_w1   = (const float*)d_in[27];
  const float* exp_b1   = (const float*)d_in[28];
  const float* exp_w2   = (const float*)d_in[29];
  const float* exp_b2   = (const float*)d_in[30];
  const float* gate_f_w = (const float*)d_in[31];
  const float* gate_f_b = (const float*)d_in[32];
  const float* gate_fail_w = (const float*)d_in[33];
  const float* gate_fail_b = (const float*)d_in[34];
  const float* gate_rca_w  = (const float*)d_in[35];
  const float* gate_rca_b  = (const float*)d_in[36];
  const float* pred_w   = (const float*)d_in[37];
  const float* pred_b   = (const float*)d_in[38];
  const float* fail_w   = (const float*)d_in[39];
  const float* fail_b   = (const float*)d_in[40];
  const float* rca_w    = (const float*)d_in[41];
  const float* rca_b    = (const float*)d_in[42];
  float* out = (float*)d_out;
  float* W = (float*)d_ws;

  // ---- workspace layout (float offsets); total ~2.5 MB ----
  const size_t o_pooled  = 0;          // 1024*64
  const size_t o_stlast  = 65536;      // 1024*64
  const size_t o_ctx     = 131072;     // 1024*128
  const size_t o_moef    = 262144;     // 32*128
  const size_t o_moerca  = 266240;     // 1024*128
  const size_t o_logitsf = 397312;     // 32*16
  const size_t o_tif     = 397824;     // 64 ints
  const size_t o_twrca   = 397888;     // 2048
  const size_t o_tirca   = 399936;     // 2048 ints
  const size_t o_petab   = 401984;     // 512*64
  unsigned short* wfragU = (unsigned short*)(W + 434752);   // 786432 B

  // 1. weight fragments + PE table
  init_kernel<<<512, 256, 0, stream>>>(tcn_w1, tcn_w2, wfragU, W + o_petab);

  // 2. persistent per-sequence TCN (proj + 4 layers + LN/pool, all in LDS)
  tcn_persist_kernel<<<1024, 1024, 0, stream>>>(
      x, wfragU, tcn_b1, tcn_b2, W + o_petab, proj_w, proj_b,
      tcn_ln_g, tcn_ln_b, mask, W + o_pooled, W + o_stlast);

  // 3. fused tail
  batch_kernel<<<32, 1024, 0, stream>>>(
      W + o_pooled, mask, pool_w, pool_b, pos_inter,
      tx_ln1_g, tx_ln1_b, tx_qkv_w, tx_qkv_b, tx_out_w, tx_out_b,
      tx_ln2_g, tx_ln2_b, tx_ff1_w, tx_ff1_b, tx_ff2_w, tx_ff2_b,
      tx_fln_g, tx_fln_b,
      exp_w1, exp_b1, exp_w2, exp_b2,
      gate_f_w, gate_f_b, gate_fail_w, gate_fail_b, fail_w, fail_b,
      W + o_ctx, W + o_moef, W + o_logitsf, (int*)(W + o_tif), out);

  // 4. rca path
  gate_kernel<<<16, 64, 0, stream>>>(W + o_ctx, gate_rca_w, gate_rca_b, 1024, 128,
                                     (int*)(W + o_tirca), W + o_twrca, nullptr);
  moe_expert_kernel<<<1024, 256, 0, stream>>>(W + o_ctx, (int*)(W + o_tirca), W + o_twrca,
                                              exp_w1, exp_b1, exp_w2, exp_b2, mask, W + o_moerca);

  // 5. aux + heads
  aux_kernel<<<1, 64, 0, stream>>>(W + o_logitsf, (int*)(W + o_tif), out + 4192);
  heads_kernel<<<4, 256, 0, stream>>>(W + o_stlast, W + o_ctx, W + o_moef, W + o_moerca,
                                      pred_w, pred_b, rca_w, rca_b, out);
}

// Round 10
// 921.654 us; speedup vs baseline: 1.1997x; 1.1997x over previous
//
#include <hip/hip_runtime.h>
#include <hip/hip_bf16.h>
#include <math.h>

typedef short short8v __attribute__((ext_vector_type(8)));
typedef float f32x4 __attribute__((ext_vector_type(4)));
typedef unsigned short ushort4v __attribute__((ext_vector_type(4)));

__device__ inline float waveReduceSum(float v){
  #pragma unroll
  for (int off = 32; off > 0; off >>= 1) v += __shfl_xor(v, off, 64);
  return v;
}

// bf16 helpers (manual RNE)
__device__ inline unsigned short f2bf(float x){
  unsigned int u = __builtin_bit_cast(unsigned int, x);
  unsigned int r = (u + 0x7FFFu + ((u >> 16) & 1u)) >> 16;
  return (unsigned short)r;
}
__device__ inline float bf2f(unsigned short u){
  unsigned int w = ((unsigned int)u) << 16;
  return __builtin_bit_cast(float, w);
}

#define TCN_O_OFF 139264   // o tile after 544-row h tile

// ============================================================================
// init: TCN weight fragments (split hi/lo, MFMA A-layout) + PE table
// ============================================================================
__global__ void init_kernel(const float* __restrict__ w1, const float* __restrict__ w2,
                            unsigned short* __restrict__ wf, float* __restrict__ petab){
  int idx = blockIdx.x * 256 + threadIdx.x;
  if (idx < 98304){
    int conv = idx / 12288;
    int r = idx % 12288;
    int tap = r >> 12;
    int kk  = (r >> 11) & 1;
    int ct  = (r >> 9) & 3;
    int lane= (r >> 3) & 63;
    int j   = r & 7;
    int layer = conv >> 1;
    const float* src = (conv & 1) ? w2 : w1;
    int co = (ct << 4) + (lane & 15);
    int ci = (kk << 5) + ((lane >> 4) << 3) + j;
    float v = src[((layer * 64 + co) * 64 + ci) * 3 + tap];
    unsigned short hi = f2bf(v);
    unsigned short lo = f2bf(v - bf2f(hi));
    size_t base = (size_t)conv * 24576 + (size_t)(((tap * 2 + kk) * 4 + ct) * 2) * 512 + lane * 8 + j;
    wf[base] = hi;
    wf[base + 512] = lo;
  } else if (idx < 131072){
    int p = idx - 98304;
    int t = p >> 6, c = p & 63;
    float ang = (float)t * expf(-0.14391156831f * (float)(c & ~1));
    petab[p] = (c & 1) ? cosf(ang) : sinf(ang);
  }
}

// ============================================================================
// One TCN layer, r4-proven register shape: 8 waves = cp (co-pair) x tsub (4),
// each wave computes 2 co-tiles; A-frags [3][2][2][2] = 96 VGPR, per-chunk
// reload (L1-hit), A1 dead before A2 loads. constexpr DIL/CONVBASE.
// ============================================================================
template<int LAYER>
__device__ __forceinline__ void run_layer(
    char* lds, const unsigned short* __restrict__ wfrag,
    const float* __restrict__ b1g, const float* __restrict__ b2g,
    int lane, int cp, int tsub){
  constexpr int DIL = 1 << LAYER;
  constexpr int CONVBASE = LAYER * 2;
  const int cobase0 = ((2 * cp) << 4) + ((lane >> 4) << 2);
  const int cobase1 = ((2 * cp + 1) << 4) + ((lane >> 4) << 2);
  const f32x4 b1v0 = *(const f32x4*)(b1g + (LAYER << 6) + cobase0);
  const f32x4 b1v1 = *(const f32x4*)(b1g + (LAYER << 6) + cobase1);
  const f32x4 b2v0 = *(const f32x4*)(b2g + (LAYER << 6) + cobase0);
  const f32x4 b2v1 = *(const f32x4*)(b2g + (LAYER << 6) + cobase1);

  for (int ch = 7; ch >= 0; --ch){
    const int t0 = ch << 6;
    __syncthreads();   // h stable from previous chunk/layer; o buffer free

    // ---- A fragments for conv1 (24 short8v = 96 VGPR, matches r4) ----
    short8v A1[3][2][2][2];
    #pragma unroll
    for (int tap = 0; tap < 3; ++tap)
      #pragma unroll
      for (int kk = 0; kk < 2; ++kk)
        #pragma unroll
        for (int cc = 0; cc < 2; ++cc)
          #pragma unroll
          for (int pl = 0; pl < 2; ++pl){
            int ct = 2 * cp + cc;
            A1[tap][kk][cc][pl] = *(const short8v*)(wfrag + (size_t)CONVBASE * 24576 +
                (size_t)((((tap * 2 + kk) * 4 + ct) * 2 + pl)) * 512 + lane * 8);
          }

    // ---- conv1: o rows 0..79 (t = t0-16+orow), 5 tiles over 2 passes ----
    #pragma unroll
    for (int S = 0; S < 2; ++S){
      int rbase = (S << 6) + (tsub << 4);
      if (rbase < 80){                       // wave-uniform
        f32x4 acc0 = {0.f,0.f,0.f,0.f}, acc1 = {0.f,0.f,0.f,0.f};
        int orow = rbase + (lane & 15);
        int t_o = t0 - 16 + orow;
        #pragma unroll
        for (int tap = 0; tap < 3; ++tap){
          int hr = t_o - (2 - tap) * DIL + 32;   // >= 0 (32 zero rows)
          int sw = (hr & 7) << 4;
          #pragma unroll
          for (int kk = 0; kk < 2; ++kk){
            int base = (hr << 8) + (kk << 6) + ((lane >> 4) << 4);
            short8v Bhi = *(const short8v*)(lds + (base ^ sw));
            short8v Blo = *(const short8v*)(lds + ((base + 128) ^ sw));
            acc0 = __builtin_amdgcn_mfma_f32_16x16x32_bf16(A1[tap][kk][0][0], Bhi, acc0, 0, 0, 0);
            acc0 = __builtin_amdgcn_mfma_f32_16x16x32_bf16(A1[tap][kk][0][0], Blo, acc0, 0, 0, 0);
            acc0 = __builtin_amdgcn_mfma_f32_16x16x32_bf16(A1[tap][kk][0][1], Bhi, acc0, 0, 0, 0);
            acc1 = __builtin_amdgcn_mfma_f32_16x16x32_bf16(A1[tap][kk][1][0], Bhi, acc1, 0, 0, 0);
            acc1 = __builtin_amdgcn_mfma_f32_16x16x32_bf16(A1[tap][kk][1][0], Blo, acc1, 0, 0, 0);
            acc1 = __builtin_amdgcn_mfma_f32_16x16x32_bf16(A1[tap][kk][1][1], Bhi, acc1, 0, 0, 0);
          }
        }
        int swO = (orow & 7) << 4;
        #pragma unroll
        for (int cc = 0; cc < 2; ++cc){
          int cobase = (cc == 0) ? cobase0 : cobase1;
          ushort4v hi4, lo4;
          #pragma unroll
          for (int r = 0; r < 4; ++r){
            float a = (cc == 0) ? acc0[r] : acc1[r];
            float bv = (cc == 0) ? b1v0[r] : b1v1[r];
            float v = fmaxf(a + bv, 0.f);
            if (t_o < 0) v = 0.f;
            unsigned short h = f2bf(v);
            hi4[r] = h;
            lo4[r] = f2bf(v - bf2f(h));
          }
          int ob = TCN_O_OFF + (orow << 8) + (cobase << 1);
          *(ushort4v*)(lds + (ob ^ swO)) = hi4;
          *(ushort4v*)(lds + ((ob + 128) ^ swO)) = lo4;
        }
      }
    }

    // ---- A fragments for conv2 (A1 dead here) ----
    short8v A2[3][2][2][2];
    #pragma unroll
    for (int tap = 0; tap < 3; ++tap)
      #pragma unroll
      for (int kk = 0; kk < 2; ++kk)
        #pragma unroll
        for (int cc = 0; cc < 2; ++cc)
          #pragma unroll
          for (int pl = 0; pl < 2; ++pl){
            int ct = 2 * cp + cc;
            A2[tap][kk][cc][pl] = *(const short8v*)(wfrag + (size_t)(CONVBASE + 1) * 24576 +
                (size_t)((((tap * 2 + kk) * 4 + ct) * 2 + pl)) * 512 + lane * 8);
          }
    __syncthreads();   // o writes visible

    // ---- conv2: outputs t0..t0+63 (4 t-tiles x 2 cp = 8 waves) ----
    {
      f32x4 acc0 = {0.f,0.f,0.f,0.f}, acc1 = {0.f,0.f,0.f,0.f};
      int tt = (tsub << 4) + (lane & 15);
      #pragma unroll
      for (int tap = 0; tap < 3; ++tap){
        int ol = tt + 16 - (2 - tap) * DIL;   // local o row 0..79
        int sw = (ol & 7) << 4;
        #pragma unroll
        for (int kk = 0; kk < 2; ++kk){
          int base = TCN_O_OFF + (ol << 8) + (kk << 6) + ((lane >> 4) << 4);
          short8v Bhi = *(const short8v*)(lds + (base ^ sw));
          short8v Blo = *(const short8v*)(lds + ((base + 128) ^ sw));
          acc0 = __builtin_amdgcn_mfma_f32_16x16x32_bf16(A2[tap][kk][0][0], Bhi, acc0, 0, 0, 0);
          acc0 = __builtin_amdgcn_mfma_f32_16x16x32_bf16(A2[tap][kk][0][0], Blo, acc0, 0, 0, 0);
          acc0 = __builtin_amdgcn_mfma_f32_16x16x32_bf16(A2[tap][kk][0][1], Bhi, acc0, 0, 0, 0);
          acc1 = __builtin_amdgcn_mfma_f32_16x16x32_bf16(A2[tap][kk][1][0], Bhi, acc1, 0, 0, 0);
          acc1 = __builtin_amdgcn_mfma_f32_16x16x32_bf16(A2[tap][kk][1][0], Blo, acc1, 0, 0, 0);
          acc1 = __builtin_amdgcn_mfma_f32_16x16x32_bf16(A2[tap][kk][1][1], Bhi, acc1, 0, 0, 0);
        }
      }
      // h' = relu(relu(acc+b2) + h_old), in place (lane reads+writes own addr)
      int hr = t0 + tt + 32;
      int swH = (hr & 7) << 4;
      #pragma unroll
      for (int cc = 0; cc < 2; ++cc){
        int cobase = (cc == 0) ? cobase0 : cobase1;
        int rb = (hr << 8) + (cobase << 1);
        ushort4v rhi = *(const ushort4v*)(lds + (rb ^ swH));
        ushort4v rlo = *(const ushort4v*)(lds + ((rb + 128) ^ swH));
        ushort4v hi4, lo4;
        #pragma unroll
        for (int r = 0; r < 4; ++r){
          float a = (cc == 0) ? acc0[r] : acc1[r];
          float bv = (cc == 0) ? b2v0[r] : b2v1[r];
          float v = fmaxf(a + bv, 0.f);
          v = fmaxf(v + bf2f(rhi[r]) + bf2f(rlo[r]), 0.f);
          unsigned short h = f2bf(v);
          hi4[r] = h;
          lo4[r] = f2bf(v - bf2f(h));
        }
        *(ushort4v*)(lds + (rb ^ swH)) = hi4;
        *(ushort4v*)(lds + ((rb + 128) ^ swH)) = lo4;
      }
    }
  }
}

// ============================================================================
// Persistent per-sequence TCN: proj+PE -> 4 layers (all in LDS) -> LN+pool.
// 1024 blocks x 512 threads (8 waves, r4-proven codegen shape, no VGPR cap).
// LDS: h 544x256 + o 80x256 = 159744 B -> 1 block/CU.
// Reverse chunk order makes in-place h overwrite safe (causal convs).
// ============================================================================
__global__ __launch_bounds__(512, 2) void tcn_persist_kernel(
    const float* __restrict__ x, const unsigned short* __restrict__ wfrag,
    const float* __restrict__ b1g, const float* __restrict__ b2g,
    const float* __restrict__ petab,
    const float* __restrict__ pw, const float* __restrict__ pb,
    const float* __restrict__ lng, const float* __restrict__ lnb,
    const float* __restrict__ maskg,
    float* __restrict__ pooled, float* __restrict__ stlast){
  __shared__ __align__(16) char lds[159744];
  const int tid = threadIdx.x;
  const int lane = tid & 63, wid = tid >> 6;   // 8 waves
  const int cp = wid & 1, tsub = wid >> 1;
  const int bn = blockIdx.x;
  const int bb = bn >> 5, nn = bn & 31;

  // ---- stage proj + PE into h rows 0..543 (t = row-32; zeros for t<0) ----
  for (int i = 0; i < 9; ++i){
    int idx = tid + i * 512;
    if (idx < 4352){
      int row = idx >> 3, cg = idx & 7;
      int t = row - 32;
      short8v vh = {0,0,0,0,0,0,0,0}, vl = {0,0,0,0,0,0,0,0};
      if (t >= 0){
        float xv = x[((size_t)bb << 14) + (t << 5) + nn];
        const float* per = petab + t * 64 + cg * 8;
        #pragma unroll
        for (int j = 0; j < 8; ++j){
          int c = cg * 8 + j;
          float val = fmaf(xv, pw[c], pb[c]) + per[j];
          unsigned short h = f2bf(val);
          vh[j] = (short)h;
          vl[j] = (short)f2bf(val - bf2f(h));
        }
      }
      int sw = (row & 7) << 4;
      int base = (row << 8) + (cg << 4);
      *(short8v*)(lds + (base ^ sw)) = vh;
      *(short8v*)(lds + ((base + 128) ^ sw)) = vl;
    }
  }

  run_layer<0>(lds, wfrag, b1g, b2g, lane, cp, tsub);
  run_layer<1>(lds, wfrag, b1g, b2g, lane, cp, tsub);
  run_layer<2>(lds, wfrag, b1g, b2g, lane, cp, tsub);
  run_layer<3>(lds, wfrag, b1g, b2g, lane, cp, tsub);

  __syncthreads();
  // ---- LN over channels + masked mean-pool + st_last ----
  {
    int s8 = tid >> 6, c = tid & 63;           // 8 groups x 64 rows
    float gc = lng[c], bc = lnb[c];
    float mk = maskg[bn];
    float acc = 0.f;
    for (int r0 = 0; r0 < 64; ++r0){
      int row = (s8 << 6) + r0;                // 0..511
      int hr = row + 32;
      int sw = (hr & 7) << 4;
      int base = (hr << 8) + (c << 1);
      float hi = bf2f(*(const unsigned short*)(lds + (base ^ sw)));
      float lo = bf2f(*(const unsigned short*)(lds + ((base + 128) ^ sw)));
      float val = hi + lo;
      float sum = val, sq = val * val;
      #pragma unroll
      for (int off = 32; off > 0; off >>= 1){
        sum += __shfl_xor(sum, off, 64);
        sq  += __shfl_xor(sq, off, 64);
      }
      float mean = sum * (1.f / 64.f);
      float var = sq * (1.f / 64.f) - mean * mean;
      float rstd = rsqrtf(var + 1e-5f);
      float o = (val - mean) * rstd * gc + bc;
      acc += o;
      if (row == 511) stlast[(size_t)bn * 64 + c] = o * mk;
    }
    __syncthreads();   // all h reads done; o-tile region reusable for partials
    *(float*)(lds + TCN_O_OFF + ((s8 << 6) + c) * 4) = acc;
    __syncthreads();
    if (tid < 64){
      float tot = 0.f;
      #pragma unroll
      for (int ss = 0; ss < 8; ++ss) tot += *(const float*)(lds + TCN_O_OFF + ((ss << 6) + tid) * 4);
      pooled[(size_t)bn * 64 + tid] = tot * (1.f / 512.f) * mk;
    }
  }
}

// ============================================================================
// Fused per-batch tail, 32 blocks x 1024 threads.
// ============================================================================
__global__ __launch_bounds__(1024) void batch_kernel(
    const float* __restrict__ pooled, const float* __restrict__ maskg,
    const float* __restrict__ pool_w, const float* __restrict__ pool_b,
    const float* __restrict__ pos,
    const float* __restrict__ ln1g, const float* __restrict__ ln1b,
    const float* __restrict__ qkvw, const float* __restrict__ qkvb_g,
    const float* __restrict__ outw, const float* __restrict__ outb,
    const float* __restrict__ ln2g, const float* __restrict__ ln2b,
    const float* __restrict__ ff1w, const float* __restrict__ ff1b,
    const float* __restrict__ ff2w, const float* __restrict__ ff2b,
    const float* __restrict__ flng, const float* __restrict__ flnb,
    const float* __restrict__ ew1, const float* __restrict__ eb1,
    const float* __restrict__ ew2, const float* __restrict__ eb2,
    const float* __restrict__ gfw, const float* __restrict__ gfb,
    const float* __restrict__ gfailw, const float* __restrict__ gfailb,
    const float* __restrict__ failw, const float* __restrict__ failb,
    float* __restrict__ ctxg, float* __restrict__ moefg,
    float* __restrict__ logitsfg, int* __restrict__ tifg,
    float* __restrict__ outg){
  __shared__ float zf[32][128];
  __shared__ float ybuf[32][128];
  __shared__ float qkvb[32][385];
  __shared__ float sc[8][33][33];
  __shared__ float ps[32][64];
  __shared__ float msk[32];
  __shared__ float rin[256];
  __shared__ float meanc[128];
  __shared__ float h1all[4][256];
  __shared__ float oall[4][128];
  __shared__ float lf[16], lfail[16];
  __shared__ int   tisel[4];
  __shared__ float twsel[4];
  __shared__ float moefail[128];
  __shared__ float cntS;

  const int b = blockIdx.x;
  const int tid = threadIdx.x;
  const int lane = tid & 63;

  if (tid < 32) msk[tid] = maskg[b * 32 + tid];
  #pragma unroll
  for (int i = 0; i < 2; ++i){
    int item = tid + 1024 * i;
    int n = item >> 6, c = item & 63;
    ps[n][c] = pooled[(size_t)(b * 32 + n) * 64 + c];
  }
  __syncthreads();

  // z init
  {
    int jb = tid & 63, nb = tid >> 6;
    float acc[2][2];
    #pragma unroll
    for (int nn = 0; nn < 2; ++nn)
      #pragma unroll
      for (int jj = 0; jj < 2; ++jj){
        int d = jb * 2 + jj, n = nb * 2 + nn;
        acc[nn][jj] = pool_b[d] + pos[n * 128 + d];
      }
    #pragma unroll 8
    for (int k = 0; k < 64; ++k){
      float w0 = pool_w[k * 128 + jb * 2], w1 = pool_w[k * 128 + jb * 2 + 1];
      #pragma unroll
      for (int nn = 0; nn < 2; ++nn){
        float y = ps[nb * 2 + nn][k];
        acc[nn][0] += y * w0; acc[nn][1] += y * w1;
      }
    }
    #pragma unroll
    for (int nn = 0; nn < 2; ++nn){
      zf[nb * 2 + nn][jb * 2]     = acc[nn][0];
      zf[nb * 2 + nn][jb * 2 + 1] = acc[nn][1];
    }
  }
  __syncthreads();

  for (int l = 0; l < 2; ++l){
    const float* Wq = qkvw + (size_t)l * 49152;
    const float* bq = qkvb_g + l * 384;
    const float* Wo = outw + (size_t)l * 16384;
    const float* bo = outb + l * 128;
    const float* W1 = ff1w + (size_t)l * 32768;
    const float* bf1 = ff1b + l * 256;
    const float* W2 = ff2w + (size_t)l * 32768;
    const float* bf2 = ff2b + l * 128;
    const float* g1 = ln1g + l * 128; const float* bb1 = ln1b + l * 128;
    const float* g2 = ln2g + l * 128; const float* bb2 = ln2b + l * 128;

    // LN1
    #pragma unroll
    for (int rr = 0; rr < 2; ++rr){
      int row = (tid >> 6) * 2 + rr;
      float x0 = zf[row][lane], x1 = zf[row][lane + 64];
      float mean = waveReduceSum(x0 + x1) * (1.f / 128.f);
      float d0 = x0 - mean, d1 = x1 - mean;
      float var = waveReduceSum(d0 * d0 + d1 * d1) * (1.f / 128.f);
      float rstd = rsqrtf(var + 1e-5f);
      ybuf[row][lane]      = d0 * rstd * g1[lane] + bb1[lane];
      ybuf[row][lane + 64] = d1 * rstd * g1[lane + 64] + bb1[lane + 64];
    }
    __syncthreads();

    // qkv
    {
      int jb = tid & 127, nb = tid >> 7;
      float acc[4][3];
      #pragma unroll
      for (int nn = 0; nn < 4; ++nn)
        #pragma unroll
        for (int jj = 0; jj < 3; ++jj) acc[nn][jj] = 0.f;
      #pragma unroll 8
      for (int k = 0; k < 128; ++k){
        float w0 = Wq[k * 384 + jb * 3], w1 = Wq[k * 384 + jb * 3 + 1], w2v = Wq[k * 384 + jb * 3 + 2];
        #pragma unroll
        for (int nn = 0; nn < 4; ++nn){
          float y = ybuf[nb * 4 + nn][k];
          acc[nn][0] += y * w0; acc[nn][1] += y * w1; acc[nn][2] += y * w2v;
        }
      }
      #pragma unroll
      for (int nn = 0; nn < 4; ++nn)
        #pragma unroll
        for (int jj = 0; jj < 3; ++jj)
          qkvb[nb * 4 + nn][jb * 3 + jj] = acc[nn][jj] + bq[jb * 3 + jj];
    }
    __syncthreads();

    // scores
    #pragma unroll
    for (int i = 0; i < 8; ++i){
      int item = tid + 1024 * i;
      int hh = item >> 10, qi = (item >> 5) & 31, ki = item & 31;
      float a = 0.f;
      #pragma unroll
      for (int d = 0; d < 16; ++d) a += qkvb[qi][hh * 16 + d] * qkvb[ki][128 + hh * 16 + d];
      a *= 0.25f;
      if (msk[ki] == 0.f) a = -1e9f;
      sc[hh][qi][ki] = a;
    }
    __syncthreads();
    // softmax
    {
      int row = tid >> 2, q4 = tid & 3;
      int hh = row >> 5, qi = row & 31;
      float v[8];
      float m = -1e30f;
      #pragma unroll
      for (int j = 0; j < 8; ++j){ v[j] = sc[hh][qi][q4 * 8 + j]; m = fmaxf(m, v[j]); }
      m = fmaxf(m, __shfl_xor(m, 1, 64));
      m = fmaxf(m, __shfl_xor(m, 2, 64));
      float s = 0.f;
      #pragma unroll
      for (int j = 0; j < 8; ++j){ v[j] = expf(v[j] - m); s += v[j]; }
      s += __shfl_xor(s, 1, 64);
      s += __shfl_xor(s, 2, 64);
      float inv = 1.f / s;
      #pragma unroll
      for (int j = 0; j < 8; ++j) sc[hh][qi][q4 * 8 + j] = v[j] * inv;
    }
    __syncthreads();
    // o -> ybuf
    #pragma unroll
    for (int i = 0; i < 4; ++i){
      int item = tid + 1024 * i;
      int n = item >> 7, dd = item & 127, hh = dd >> 4;
      float o = 0.f;
      #pragma unroll
      for (int ki = 0; ki < 32; ++ki) o += sc[hh][n][ki] * qkvb[ki][256 + dd];
      ybuf[n][dd] = o;
    }
    __syncthreads();

    // z += o @ Wo + bo
    {
      int jb = tid & 63, nb = tid >> 6;
      float acc[2][2];
      #pragma unroll
      for (int nn = 0; nn < 2; ++nn){ acc[nn][0] = 0.f; acc[nn][1] = 0.f; }
      #pragma unroll 8
      for (int k = 0; k < 128; ++k){
        float w0 = Wo[k * 128 + jb * 2], w1 = Wo[k * 128 + jb * 2 + 1];
        #pragma unroll
        for (int nn = 0; nn < 2; ++nn){
          float y = ybuf[nb * 2 + nn][k];
          acc[nn][0] += y * w0; acc[nn][1] += y * w1;
        }
      }
      #pragma unroll
      for (int nn = 0; nn < 2; ++nn){
        zf[nb * 2 + nn][jb * 2]     += acc[nn][0] + bo[jb * 2];
        zf[nb * 2 + nn][jb * 2 + 1] += acc[nn][1] + bo[jb * 2 + 1];
      }
    }
    __syncthreads();

    // LN2
    #pragma unroll
    for (int rr = 0; rr < 2; ++rr){
      int row = (tid >> 6) * 2 + rr;
      float x0 = zf[row][lane], x1 = zf[row][lane + 64];
      float mean = waveReduceSum(x0 + x1) * (1.f / 128.f);
      float d0 = x0 - mean, d1 = x1 - mean;
      float var = waveReduceSum(d0 * d0 + d1 * d1) * (1.f / 128.f);
      float rstd = rsqrtf(var + 1e-5f);
      ybuf[row][lane]      = d0 * rstd * g2[lane] + bb2[lane];
      ybuf[row][lane + 64] = d1 * rstd * g2[lane + 64] + bb2[lane + 64];
    }
    __syncthreads();

    // ff1
    {
      int jb = tid & 127, nb = tid >> 7;
      float acc[4][2];
      #pragma unroll
      for (int nn = 0; nn < 4; ++nn){ acc[nn][0] = 0.f; acc[nn][1] = 0.f; }
      #pragma unroll 8
      for (int k = 0; k < 128; ++k){
        float w0 = W1[k * 256 + jb * 2], w1 = W1[k * 256 + jb * 2 + 1];
        #pragma unroll
        for (int nn = 0; nn < 4; ++nn){
          float y = ybuf[nb * 4 + nn][k];
          acc[nn][0] += y * w0; acc[nn][1] += y * w1;
        }
      }
      #pragma unroll
      for (int nn = 0; nn < 4; ++nn){
        qkvb[nb * 4 + nn][jb * 2]     = fmaxf(acc[nn][0] + bf1[jb * 2], 0.f);
        qkvb[nb * 4 + nn][jb * 2 + 1] = fmaxf(acc[nn][1] + bf1[jb * 2 + 1], 0.f);
      }
    }
    __syncthreads();

    // z += ff @ W2 + bf2
    {
      int jb = tid & 63, nb = tid >> 6;
      float acc[2][2];
      #pragma unroll
      for (int nn = 0; nn < 2; ++nn){ acc[nn][0] = 0.f; acc[nn][1] = 0.f; }
      #pragma unroll 8
      for (int k = 0; k < 256; ++k){
        float w0 = W2[k * 128 + jb * 2], w1 = W2[k * 128 + jb * 2 + 1];
        #pragma unroll
        for (int nn = 0; nn < 2; ++nn){
          float y = qkvb[nb * 2 + nn][k];
          acc[nn][0] += y * w0; acc[nn][1] += y * w1;
        }
      }
      #pragma unroll
      for (int nn = 0; nn < 2; ++nn){
        zf[nb * 2 + nn][jb * 2]     += acc[nn][0] + bf2[jb * 2];
        zf[nb * 2 + nn][jb * 2 + 1] += acc[nn][1] + bf2[jb * 2 + 1];
      }
    }
    __syncthreads();
  }

  // final LN * mask -> ybuf + ctx
  #pragma unroll
  for (int rr = 0; rr < 2; ++rr){
    int row = (tid >> 6) * 2 + rr;
    float x0 = zf[row][lane], x1 = zf[row][lane + 64];
    float mean = waveReduceSum(x0 + x1) * (1.f / 128.f);
    float d0 = x0 - mean, d1 = x1 - mean;
    float var = waveReduceSum(d0 * d0 + d1 * d1) * (1.f / 128.f);
    float rstd = rsqrtf(var + 1e-5f);
    float mk = msk[row];
    ybuf[row][lane]      = (d0 * rstd * flng[lane] + flnb[lane]) * mk;
    ybuf[row][lane + 64] = (d1 * rstd * flng[lane + 64] + flnb[lane + 64]) * mk;
  }
  if (tid == 0){
    float c = 0.f;
    for (int n = 0; n < 32; ++n) c += maskg[b * 32 + n];
    cntS = fmaxf(c, 1.f);
  }
  __syncthreads();
  #pragma unroll
  for (int i = 0; i < 4; ++i){
    int item = tid + 1024 * i;
    int n = item >> 7, d = item & 127;
    ctxg[(size_t)(b * 32 + n) * 128 + d] = ybuf[n][d];
  }
  if (tid < 128){
    float s = 0.f, s2 = 0.f;
    #pragma unroll 8
    for (int n = 0; n < 32; ++n){ float v = ybuf[n][tid]; s += v; s2 += v * v; }
    float mean = s / cntS;
    float var = s2 / cntS - mean * mean;
    meanc[tid] = mean;
    rin[tid] = mean;
    rin[128 + tid] = sqrtf(fmaxf(var, 1e-6f));
  }
  __syncthreads();
  // gates
  {
    int g = tid >> 9;
    int e = (tid >> 5) & 15, kk = tid & 31;
    const float* gw = g ? gfailw : gfw;
    float a = 0.f;
    #pragma unroll
    for (int j = 0; j < 8; ++j){
      int k = kk * 8 + j;
      a += rin[k] * gw[k * 16 + e];
    }
    a += __shfl_xor(a, 1, 64);  a += __shfl_xor(a, 2, 64);
    a += __shfl_xor(a, 4, 64);  a += __shfl_xor(a, 8, 64);
    a += __shfl_xor(a, 16, 64);
    if (kk == 0){
      if (g == 0){
        float r = a + gfb[e];
        lf[e] = r;
        logitsfg[b * 16 + e] = r;
      } else {
        lfail[e] = a + gfailb[e];
      }
    }
  }
  __syncthreads();
  if (tid < 2){
    const float* lg = (tid == 0) ? lf : lfail;
    int i0 = 0; float v0 = lg[0];
    for (int e = 1; e < 16; ++e) if (lg[e] > v0){ v0 = lg[e]; i0 = e; }
    int i1 = -1; float v1 = -1e30f;
    for (int e = 0; e < 16; ++e) if (e != i0 && lg[e] > v1){ v1 = lg[e]; i1 = e; }
    float e1 = expf(v1 - v0);
    float den = 1.f / (1.f + e1);
    tisel[tid * 2] = i0; tisel[tid * 2 + 1] = i1;
    twsel[tid * 2] = den; twsel[tid * 2 + 1] = e1 * den;
    if (tid == 0){ tifg[b * 2] = i0; tifg[b * 2 + 1] = i1; }
  }
  __syncthreads();
  // MoE: 4 selected experts in parallel
  {
    int sel = tid >> 8, h = tid & 255;
    int e = tisel[sel];
    float a = eb1[e * 256 + h];
    #pragma unroll 8
    for (int k = 0; k < 128; ++k) a += meanc[k] * ew1[(size_t)(e * 128 + k) * 256 + h];
    h1all[sel][h] = fmaxf(a, 0.f);
  }
  __syncthreads();
  if (tid < 512){
    int sel = tid >> 7, d = tid & 127;
    int e = tisel[sel];
    float o = eb2[e * 128 + d];
    #pragma unroll 8
    for (int k = 0; k < 256; ++k) o += h1all[sel][k] * ew2[(size_t)(e * 256 + k) * 128 + d];
    oall[sel][d] = twsel[sel] * o;
  }
  __syncthreads();
  if (tid < 128){
    moefg[b * 128 + tid] = oall[0][tid] + oall[1][tid];
    moefail[tid] = oall[2][tid] + oall[3][tid];
  }
  __syncthreads();
  if (tid < 3){
    float a = failb[tid];
    for (int k = 0; k < 128; ++k) a += moefail[k] * failw[k * 3 + tid];
    outg[3072 + b * 3 + tid] = a;
  }
}

// ---------------- gate (rca) ----------------
__global__ void gate_kernel(const float* __restrict__ gin, const float* __restrict__ gw,
                            const float* __restrict__ gb, int ntok, int K,
                            int* __restrict__ ti, float* __restrict__ tw,
                            float* __restrict__ logits_out){
  int tok = blockIdx.x * 64 + threadIdx.x;
  if (tok >= ntok) return;
  float acc[16];
  #pragma unroll
  for (int e = 0; e < 16; ++e) acc[e] = gb[e];
  const float* gr = gin + (size_t)tok * K;
  #pragma unroll 4
  for (int k = 0; k < K; ++k){
    float gv = gr[k];
    #pragma unroll
    for (int e = 0; e < 16; ++e) acc[e] = fmaf(gv, gw[k*16 + e], acc[e]);
  }
  if (logits_out){
    #pragma unroll
    for (int e = 0; e < 16; ++e) logits_out[tok*16 + e] = acc[e];
  }
  int i0 = 0; float v0 = acc[0];
  #pragma unroll
  for (int e = 1; e < 16; ++e) if (acc[e] > v0){ v0 = acc[e]; i0 = e; }
  int i1 = -1; float v1 = -1e30f;
  #pragma unroll
  for (int e = 0; e < 16; ++e) if (e != i0 && acc[e] > v1){ v1 = acc[e]; i1 = e; }
  float e1 = expf(v1 - v0);
  float den = 1.f / (1.f + e1);
  ti[tok*2] = i0; ti[tok*2+1] = i1;
  tw[tok*2] = den; tw[tok*2+1] = e1 * den;
}

// ---------------- MoE expert eval (rca) ----------------
__global__ void moe_expert_kernel(const float* __restrict__ xin, const int* __restrict__ ti,
                                  const float* __restrict__ tw,
                                  const float* __restrict__ w1, const float* __restrict__ b1,
                                  const float* __restrict__ w2, const float* __restrict__ b2,
                                  const float* __restrict__ mask, float* __restrict__ yout){
  int tok = blockIdx.x;
  int tid = threadIdx.x; // 256
  __shared__ float xs[128];
  __shared__ float h1[256];
  if (tid < 128) xs[tid] = xin[(size_t)tok*128 + tid];
  __syncthreads();
  float accv = 0.f;
  for (int kkk = 0; kkk < 2; ++kkk){
    int e = ti[tok*2 + kkk];
    float wv = tw[tok*2 + kkk];
    float a = b1[e*256 + tid];
    #pragma unroll 8
    for (int k = 0; k < 128; ++k) a = fmaf(xs[k], w1[(size_t)(e*128 + k)*256 + tid], a);
    __syncthreads();
    h1[tid] = fmaxf(a, 0.f);
    __syncthreads();
    if (tid < 128){
      float o = b2[e*128 + tid];
      #pragma unroll 8
      for (int k = 0; k < 256; ++k) o = fmaf(h1[k], w2[(size_t)(e*256 + k)*128 + tid], o);
      accv += wv * o;
    }
  }
  if (tid < 128){
    if (mask) accv *= mask[tok];
    yout[(size_t)tok*128 + tid] = accv;
  }
}

// ---------------- aux loss ----------------
__global__ void aux_kernel(const float* __restrict__ logits, const int* __restrict__ ti,
                           float* __restrict__ out_scalar){
  if (threadIdx.x != 0 || blockIdx.x != 0) return;
  float pm[16];
  for (int e = 0; e < 16; ++e) pm[e] = 0.f;
  for (int i = 0; i < 32; ++i){
    const float* row = logits + i*16;
    float m = -1e30f;
    for (int e = 0; e < 16; ++e) m = fmaxf(m, row[e]);
    float s = 0.f;
    float ex[16];
    for (int e = 0; e < 16; ++e){ ex[e] = expf(row[e] - m); s += ex[e]; }
    for (int e = 0; e < 16; ++e) pm[e] += ex[e] / s;
  }
  float cnt[16];
  for (int e = 0; e < 16; ++e) cnt[e] = 0.f;
  for (int i = 0; i < 64; ++i) cnt[ti[i]] += 1.f;
  float loss = 0.f;
  for (int e = 0; e < 16; ++e) loss += (pm[e] / 32.f) * (cnt[e] / 64.f);
  out_scalar[0] = 16.f * loss;
}

// ---------------- pred + rca heads ----------------
__global__ void heads_kernel(const float* __restrict__ st_last, const float* __restrict__ ctx,
                             const float* __restrict__ moe_f, const float* __restrict__ moe_rca,
                             const float* __restrict__ pred_w, const float* __restrict__ pred_b,
                             const float* __restrict__ rca_w, const float* __restrict__ rca_b,
                             float* __restrict__ out){
  int bn = blockIdx.x * 256 + threadIdx.x;
  if (bn >= 1024) return;
  int b = bn >> 5;
  float p0 = pred_b[0], p1 = pred_b[1], p2 = pred_b[2];
  float r = rca_b[0];
  #pragma unroll 4
  for (int i = 0; i < 64; ++i){
    float v = st_last[(size_t)bn*64 + i];
    p0 = fmaf(v, pred_w[i*3+0], p0); p1 = fmaf(v, pred_w[i*3+1], p1); p2 = fmaf(v, pred_w[i*3+2], p2);
    r = fmaf(v, rca_w[i], r);
  }
  #pragma unroll 4
  for (int i = 0; i < 128; ++i){
    float v = ctx[(size_t)bn*128 + i];
    int ii = 64 + i;
    p0 = fmaf(v, pred_w[ii*3+0], p0); p1 = fmaf(v, pred_w[ii*3+1], p1); p2 = fmaf(v, pred_w[ii*3+2], p2);
    r = fmaf(v, rca_w[ii], r);
  }
  #pragma unroll 4
  for (int i = 0; i < 128; ++i){
    int ii = 192 + i;
    float vp = moe_f[(size_t)b*128 + i];
    p0 = fmaf(vp, pred_w[ii*3+0], p0); p1 = fmaf(vp, pred_w[ii*3+1], p1); p2 = fmaf(vp, pred_w[ii*3+2], p2);
    float vr = moe_rca[(size_t)bn*128 + i];
    r = fmaf(vr, rca_w[ii], r);
  }
  out[bn*3+0] = p0; out[bn*3+1] = p1; out[bn*3+2] = p2;
  out[3168 + bn] = r;
}

// ================= host =================
extern "C" void kernel_launch(void* const* d_in, const int* in_sizes, int n_in,
                              void* d_out, int out_size, void* d_ws, size_t ws_size,
                              hipStream_t stream){
  const float* x        = (const float*)d_in[0];
  const float* mask     = (const float*)d_in[1];
  const float* proj_w   = (const float*)d_in[2];
  const float* proj_b   = (const float*)d_in[3];
  const float* tcn_w1   = (const float*)d_in[4];
  const float* tcn_b1   = (const float*)d_in[5];
  const float* tcn_w2   = (const float*)d_in[6];
  const float* tcn_b2   = (const float*)d_in[7];
  const float* tcn_ln_g = (const float*)d_in[8];
  const float* tcn_ln_b = (const float*)d_in[9];
  const float* pool_w   = (const float*)d_in[10];
  const float* pool_b   = (const float*)d_in[11];
  const float* pos_inter= (const float*)d_in[12];
  const float* tx_ln1_g = (const float*)d_in[13];
  const float* tx_ln1_b = (const float*)d_in[14];
  const float* tx_qkv_w = (const float*)d_in[15];
  const float* tx_qkv_b = (const float*)d_in[16];
  const float* tx_out_w = (const float*)d_in[17];
  const float* tx_out_b = (const float*)d_in[18];
  const float* tx_ln2_g = (const float*)d_in[19];
  const float* tx_ln2_b = (const float*)d_in[20];
  const float* tx_ff1_w = (const float*)d_in[21];
  const float* tx_ff1_b = (const float*)d_in[22];
  const float* tx_ff2_w = (const float*)d_in[23];
  const float* tx_ff2_b = (const float*)d_in[24];
  const float* tx_fln_g = (const float*)d_in[25];
  const float* tx_fln_b = (const float*)d_in[26];
  const float* exp_w1   = (const float*)d_in[27];
  const float* exp_b1   = (const float*)d_in[28];
  const float* exp_w2   = (const float*)d_in[29];
  const float* exp_b2   = (const float*)d_in[30];
  const float* gate_f_w = (const float*)d_in[31];
  const float* gate_f_b = (const float*)d_in[32];
  const float* gate_fail_w = (const float*)d_in[33];
  const float* gate_fail_b = (const float*)d_in[34];
  const float* gate_rca_w  = (const float*)d_in[35];
  const float* gate_rca_b  = (const float*)d_in[36];
  const float* pred_w   = (const float*)d_in[37];
  const float* pred_b   = (const float*)d_in[38];
  const float* fail_w   = (const float*)d_in[39];
  const float* fail_b   = (const float*)d_in[40];
  const float* rca_w    = (const float*)d_in[41];
  const float* rca_b    = (const float*)d_in[42];
  float* out = (float*)d_out;
  float* W = (float*)d_ws;

  // ---- workspace layout (float offsets); total ~2.5 MB ----
  const size_t o_pooled  = 0;          // 1024*64
  const size_t o_stlast  = 65536;      // 1024*64
  const size_t o_ctx     = 131072;     // 1024*128
  const size_t o_moef    = 262144;     // 32*128
  const size_t o_moerca  = 266240;     // 1024*128
  const size_t o_logitsf = 397312;     // 32*16
  const size_t o_tif     = 397824;     // 64 ints
  const size_t o_twrca   = 397888;     // 2048
  const size_t o_tirca   = 399936;     // 2048 ints
  const size_t o_petab   = 401984;     // 512*64
  unsigned short* wfragU = (unsigned short*)(W + 434752);   // 786432 B

  // 1. weight fragments + PE table
  init_kernel<<<512, 256, 0, stream>>>(tcn_w1, tcn_w2, wfragU, W + o_petab);

  // 2. persistent per-sequence TCN (proj + 4 layers + LN/pool, all in LDS)
  tcn_persist_kernel<<<1024, 512, 0, stream>>>(
      x, wfragU, tcn_b1, tcn_b2, W + o_petab, proj_w, proj_b,
      tcn_ln_g, tcn_ln_b, mask, W + o_pooled, W + o_stlast);

  // 3. fused tail
  batch_kernel<<<32, 1024, 0, stream>>>(
      W + o_pooled, mask, pool_w, pool_b, pos_inter,
      tx_ln1_g, tx_ln1_b, tx_qkv_w, tx_qkv_b, tx_out_w, tx_out_b,
      tx_ln2_g, tx_ln2_b, tx_ff1_w, tx_ff1_b, tx_ff2_w, tx_ff2_b,
      tx_fln_g, tx_fln_b,
      exp_w1, exp_b1, exp_w2, exp_b2,
      gate_f_w, gate_f_b, gate_fail_w, gate_fail_b, fail_w, fail_b,
      W + o_ctx, W + o_moef, W + o_logitsf, (int*)(W + o_tif), out);

  // 4. rca path
  gate_kernel<<<16, 64, 0, stream>>>(W + o_ctx, gate_rca_w, gate_rca_b, 1024, 128,
                                     (int*)(W + o_tirca), W + o_twrca, nullptr);
  moe_expert_kernel<<<1024, 256, 0, stream>>>(W + o_ctx, (int*)(W + o_tirca), W + o_twrca,
                                              exp_w1, exp_b1, exp_w2, exp_b2, mask, W + o_moerca);

  // 5. aux + heads
  aux_kernel<<<1, 64, 0, stream>>>(W + o_logitsf, (int*)(W + o_tif), out + 4192);
  heads_kernel<<<4, 256, 0, stream>>>(W + o_stlast, W + o_ctx, W + o_moef, W + o_moerca,
                                      pred_w, pred_b, rca_w, rca_b, out);
}

// Round 11
// 912.816 us; speedup vs baseline: 1.2113x; 1.0097x over previous
//
#include <hip/hip_runtime.h>
#include <hip/hip_bf16.h>
#include <math.h>

typedef short short8v __attribute__((ext_vector_type(8)));
typedef float f32x4 __attribute__((ext_vector_type(4)));
typedef unsigned short ushort4v __attribute__((ext_vector_type(4)));

__device__ inline float waveReduceSum(float v){
  #pragma unroll
  for (int off = 32; off > 0; off >>= 1) v += __shfl_xor(v, off, 64);
  return v;
}

// bf16 helpers (manual RNE)
__device__ inline unsigned short f2bf(float x){
  unsigned int u = __builtin_bit_cast(unsigned int, x);
  unsigned int r = (u + 0x7FFFu + ((u >> 16) & 1u)) >> 16;
  return (unsigned short)r;
}
__device__ inline float bf2f(unsigned short u){
  unsigned int w = ((unsigned int)u) << 16;
  return __builtin_bit_cast(float, w);
}

#define TCN_O_OFF 139264   // o tile after 544-row h tile

// ============================================================================
// init: TCN weight fragments (split hi/lo, MFMA A-layout) + PE table
// ============================================================================
__global__ void init_kernel(const float* __restrict__ w1, const float* __restrict__ w2,
                            unsigned short* __restrict__ wf, float* __restrict__ petab){
  int idx = blockIdx.x * 256 + threadIdx.x;
  if (idx < 98304){
    int conv = idx / 12288;
    int r = idx % 12288;
    int tap = r >> 12;
    int kk  = (r >> 11) & 1;
    int ct  = (r >> 9) & 3;
    int lane= (r >> 3) & 63;
    int j   = r & 7;
    int layer = conv >> 1;
    const float* src = (conv & 1) ? w2 : w1;
    int co = (ct << 4) + (lane & 15);
    int ci = (kk << 5) + ((lane >> 4) << 3) + j;
    float v = src[((layer * 64 + co) * 64 + ci) * 3 + tap];
    unsigned short hi = f2bf(v);
    unsigned short lo = f2bf(v - bf2f(hi));
    size_t base = (size_t)conv * 24576 + (size_t)(((tap * 2 + kk) * 4 + ct) * 2) * 512 + lane * 8 + j;
    wf[base] = hi;
    wf[base + 512] = lo;
  } else if (idx < 131072){
    int p = idx - 98304;
    int t = p >> 6, c = p & 63;
    float ang = (float)t * expf(-0.14391156831f * (float)(c & ~1));
    petab[p] = (c & 1) ? cosf(ang) : sinf(ang);
  }
}

// ============================================================================
// One TCN layer, r4-proven register shape: 8 waves = cp (co-pair) x tsub (4),
// each wave computes 2 co-tiles; A-frags [3][2][2][2] = 96 VGPR, per-chunk
// reload (L1-hit), A1 dead before A2 loads. constexpr DIL/CONVBASE.
// ============================================================================
template<int LAYER>
__device__ __forceinline__ void run_layer(
    char* lds, const unsigned short* __restrict__ wfrag,
    const float* __restrict__ b1g, const float* __restrict__ b2g,
    int lane, int cp, int tsub){
  constexpr int DIL = 1 << LAYER;
  constexpr int CONVBASE = LAYER * 2;
  const int cobase0 = ((2 * cp) << 4) + ((lane >> 4) << 2);
  const int cobase1 = ((2 * cp + 1) << 4) + ((lane >> 4) << 2);
  const f32x4 b1v0 = *(const f32x4*)(b1g + (LAYER << 6) + cobase0);
  const f32x4 b1v1 = *(const f32x4*)(b1g + (LAYER << 6) + cobase1);
  const f32x4 b2v0 = *(const f32x4*)(b2g + (LAYER << 6) + cobase0);
  const f32x4 b2v1 = *(const f32x4*)(b2g + (LAYER << 6) + cobase1);

  for (int ch = 7; ch >= 0; --ch){
    const int t0 = ch << 6;
    __syncthreads();   // h stable from previous chunk/layer; o buffer free

    // ---- A fragments for conv1 (24 short8v = 96 VGPR, matches r4) ----
    short8v A1[3][2][2][2];
    #pragma unroll
    for (int tap = 0; tap < 3; ++tap)
      #pragma unroll
      for (int kk = 0; kk < 2; ++kk)
        #pragma unroll
        for (int cc = 0; cc < 2; ++cc)
          #pragma unroll
          for (int pl = 0; pl < 2; ++pl){
            int ct = 2 * cp + cc;
            A1[tap][kk][cc][pl] = *(const short8v*)(wfrag + (size_t)CONVBASE * 24576 +
                (size_t)((((tap * 2 + kk) * 4 + ct) * 2 + pl)) * 512 + lane * 8);
          }

    // ---- conv1: o rows 0..79 (t = t0-16+orow), 5 tiles over 2 passes ----
    #pragma unroll
    for (int S = 0; S < 2; ++S){
      int rbase = (S << 6) + (tsub << 4);
      if (rbase < 80){                       // wave-uniform
        f32x4 acc0 = {0.f,0.f,0.f,0.f}, acc1 = {0.f,0.f,0.f,0.f};
        int orow = rbase + (lane & 15);
        int t_o = t0 - 16 + orow;
        #pragma unroll
        for (int tap = 0; tap < 3; ++tap){
          int hr = t_o - (2 - tap) * DIL + 32;   // >= 0 (32 zero rows)
          int sw = (hr & 7) << 4;
          #pragma unroll
          for (int kk = 0; kk < 2; ++kk){
            int base = (hr << 8) + (kk << 6) + ((lane >> 4) << 4);
            short8v Bhi = *(const short8v*)(lds + (base ^ sw));
            short8v Blo = *(const short8v*)(lds + ((base + 128) ^ sw));
            acc0 = __builtin_amdgcn_mfma_f32_16x16x32_bf16(A1[tap][kk][0][0], Bhi, acc0, 0, 0, 0);
            acc0 = __builtin_amdgcn_mfma_f32_16x16x32_bf16(A1[tap][kk][0][0], Blo, acc0, 0, 0, 0);
            acc0 = __builtin_amdgcn_mfma_f32_16x16x32_bf16(A1[tap][kk][0][1], Bhi, acc0, 0, 0, 0);
            acc1 = __builtin_amdgcn_mfma_f32_16x16x32_bf16(A1[tap][kk][1][0], Bhi, acc1, 0, 0, 0);
            acc1 = __builtin_amdgcn_mfma_f32_16x16x32_bf16(A1[tap][kk][1][0], Blo, acc1, 0, 0, 0);
            acc1 = __builtin_amdgcn_mfma_f32_16x16x32_bf16(A1[tap][kk][1][1], Bhi, acc1, 0, 0, 0);
          }
        }
        int swO = (orow & 7) << 4;
        #pragma unroll
        for (int cc = 0; cc < 2; ++cc){
          int cobase = (cc == 0) ? cobase0 : cobase1;
          ushort4v hi4, lo4;
          #pragma unroll
          for (int r = 0; r < 4; ++r){
            float a = (cc == 0) ? acc0[r] : acc1[r];
            float bv = (cc == 0) ? b1v0[r] : b1v1[r];
            float v = fmaxf(a + bv, 0.f);
            if (t_o < 0) v = 0.f;
            unsigned short h = f2bf(v);
            hi4[r] = h;
            lo4[r] = f2bf(v - bf2f(h));
          }
          int ob = TCN_O_OFF + (orow << 8) + (cobase << 1);
          *(ushort4v*)(lds + (ob ^ swO)) = hi4;
          *(ushort4v*)(lds + ((ob + 128) ^ swO)) = lo4;
        }
      }
    }

    // ---- A fragments for conv2 (A1 dead here) ----
    short8v A2[3][2][2][2];
    #pragma unroll
    for (int tap = 0; tap < 3; ++tap)
      #pragma unroll
      for (int kk = 0; kk < 2; ++kk)
        #pragma unroll
        for (int cc = 0; cc < 2; ++cc)
          #pragma unroll
          for (int pl = 0; pl < 2; ++pl){
            int ct = 2 * cp + cc;
            A2[tap][kk][cc][pl] = *(const short8v*)(wfrag + (size_t)(CONVBASE + 1) * 24576 +
                (size_t)((((tap * 2 + kk) * 4 + ct) * 2 + pl)) * 512 + lane * 8);
          }
    __syncthreads();   // o writes visible

    // ---- conv2: outputs t0..t0+63 (4 t-tiles x 2 cp = 8 waves) ----
    {
      f32x4 acc0 = {0.f,0.f,0.f,0.f}, acc1 = {0.f,0.f,0.f,0.f};
      int tt = (tsub << 4) + (lane & 15);
      #pragma unroll
      for (int tap = 0; tap < 3; ++tap){
        int ol = tt + 16 - (2 - tap) * DIL;   // local o row 0..79
        int sw = (ol & 7) << 4;
        #pragma unroll
        for (int kk = 0; kk < 2; ++kk){
          int base = TCN_O_OFF + (ol << 8) + (kk << 6) + ((lane >> 4) << 4);
          short8v Bhi = *(const short8v*)(lds + (base ^ sw));
          short8v Blo = *(const short8v*)(lds + ((base + 128) ^ sw));
          acc0 = __builtin_amdgcn_mfma_f32_16x16x32_bf16(A2[tap][kk][0][0], Bhi, acc0, 0, 0, 0);
          acc0 = __builtin_amdgcn_mfma_f32_16x16x32_bf16(A2[tap][kk][0][0], Blo, acc0, 0, 0, 0);
          acc0 = __builtin_amdgcn_mfma_f32_16x16x32_bf16(A2[tap][kk][0][1], Bhi, acc0, 0, 0, 0);
          acc1 = __builtin_amdgcn_mfma_f32_16x16x32_bf16(A2[tap][kk][1][0], Bhi, acc1, 0, 0, 0);
          acc1 = __builtin_amdgcn_mfma_f32_16x16x32_bf16(A2[tap][kk][1][0], Blo, acc1, 0, 0, 0);
          acc1 = __builtin_amdgcn_mfma_f32_16x16x32_bf16(A2[tap][kk][1][1], Bhi, acc1, 0, 0, 0);
        }
      }
      // h' = relu(relu(acc+b2) + h_old), in place (lane reads+writes own addr)
      int hr = t0 + tt + 32;
      int swH = (hr & 7) << 4;
      #pragma unroll
      for (int cc = 0; cc < 2; ++cc){
        int cobase = (cc == 0) ? cobase0 : cobase1;
        int rb = (hr << 8) + (cobase << 1);
        ushort4v rhi = *(const ushort4v*)(lds + (rb ^ swH));
        ushort4v rlo = *(const ushort4v*)(lds + ((rb + 128) ^ swH));
        ushort4v hi4, lo4;
        #pragma unroll
        for (int r = 0; r < 4; ++r){
          float a = (cc == 0) ? acc0[r] : acc1[r];
          float bv = (cc == 0) ? b2v0[r] : b2v1[r];
          float v = fmaxf(a + bv, 0.f);
          v = fmaxf(v + bf2f(rhi[r]) + bf2f(rlo[r]), 0.f);
          unsigned short h = f2bf(v);
          hi4[r] = h;
          lo4[r] = f2bf(v - bf2f(h));
        }
        *(ushort4v*)(lds + (rb ^ swH)) = hi4;
        *(ushort4v*)(lds + ((rb + 128) ^ swH)) = lo4;
      }
    }
  }
}

// ============================================================================
// Persistent per-sequence TCN: proj+PE -> 4 layers (all in LDS) -> LN+pool.
// 1024 blocks x 512 threads (8 waves). LDS 159744 B -> 1 block/CU (2 waves/EU).
// amdgpu_waves_per_eu(2,2): occupancy is LDS-pinned at 2 waves/EU, so tell the
// allocator — removes its 128-VGPR occupancy heuristic that caused the
// r8/r9/r10 scratch spills (260-860 MB of FETCH/WRITE traffic).
// Reverse chunk order makes in-place h overwrite safe (causal convs).
// ============================================================================
__global__ __launch_bounds__(512)
__attribute__((amdgpu_waves_per_eu(2, 2)))
void tcn_persist_kernel(
    const float* __restrict__ x, const unsigned short* __restrict__ wfrag,
    const float* __restrict__ b1g, const float* __restrict__ b2g,
    const float* __restrict__ petab,
    const float* __restrict__ pw, const float* __restrict__ pb,
    const float* __restrict__ lng, const float* __restrict__ lnb,
    const float* __restrict__ maskg,
    float* __restrict__ pooled, float* __restrict__ stlast){
  __shared__ __align__(16) char lds[159744];
  const int tid = threadIdx.x;
  const int lane = tid & 63, wid = tid >> 6;   // 8 waves
  const int cp = wid & 1, tsub = wid >> 1;
  const int bn = blockIdx.x;
  const int bb = bn >> 5, nn = bn & 31;

  // ---- stage proj + PE into h rows 0..543 (t = row-32; zeros for t<0) ----
  for (int i = 0; i < 9; ++i){
    int idx = tid + i * 512;
    if (idx < 4352){
      int row = idx >> 3, cg = idx & 7;
      int t = row - 32;
      short8v vh = {0,0,0,0,0,0,0,0}, vl = {0,0,0,0,0,0,0,0};
      if (t >= 0){
        float xv = x[((size_t)bb << 14) + (t << 5) + nn];
        const float* per = petab + t * 64 + cg * 8;
        #pragma unroll
        for (int j = 0; j < 8; ++j){
          int c = cg * 8 + j;
          float val = fmaf(xv, pw[c], pb[c]) + per[j];
          unsigned short h = f2bf(val);
          vh[j] = (short)h;
          vl[j] = (short)f2bf(val - bf2f(h));
        }
      }
      int sw = (row & 7) << 4;
      int base = (row << 8) + (cg << 4);
      *(short8v*)(lds + (base ^ sw)) = vh;
      *(short8v*)(lds + ((base + 128) ^ sw)) = vl;
    }
  }

  run_layer<0>(lds, wfrag, b1g, b2g, lane, cp, tsub);
  run_layer<1>(lds, wfrag, b1g, b2g, lane, cp, tsub);
  run_layer<2>(lds, wfrag, b1g, b2g, lane, cp, tsub);
  run_layer<3>(lds, wfrag, b1g, b2g, lane, cp, tsub);

  __syncthreads();
  // ---- LN over channels + masked mean-pool + st_last ----
  {
    int s8 = tid >> 6, c = tid & 63;           // 8 groups x 64 rows
    float gc = lng[c], bc = lnb[c];
    float mk = maskg[bn];
    float acc = 0.f;
    for (int r0 = 0; r0 < 64; ++r0){
      int row = (s8 << 6) + r0;                // 0..511
      int hr = row + 32;
      int sw = (hr & 7) << 4;
      int base = (hr << 8) + (c << 1);
      float hi = bf2f(*(const unsigned short*)(lds + (base ^ sw)));
      float lo = bf2f(*(const unsigned short*)(lds + ((base + 128) ^ sw)));
      float val = hi + lo;
      float sum = val, sq = val * val;
      #pragma unroll
      for (int off = 32; off > 0; off >>= 1){
        sum += __shfl_xor(sum, off, 64);
        sq  += __shfl_xor(sq, off, 64);
      }
      float mean = sum * (1.f / 64.f);
      float var = sq * (1.f / 64.f) - mean * mean;
      float rstd = rsqrtf(var + 1e-5f);
      float o = (val - mean) * rstd * gc + bc;
      acc += o;
      if (row == 511) stlast[(size_t)bn * 64 + c] = o * mk;
    }
    __syncthreads();   // all h reads done; o-tile region reusable for partials
    *(float*)(lds + TCN_O_OFF + ((s8 << 6) + c) * 4) = acc;
    __syncthreads();
    if (tid < 64){
      float tot = 0.f;
      #pragma unroll
      for (int ss = 0; ss < 8; ++ss) tot += *(const float*)(lds + TCN_O_OFF + ((ss << 6) + tid) * 4);
      pooled[(size_t)bn * 64 + tid] = tot * (1.f / 512.f) * mk;
    }
  }
}

// ============================================================================
// Fused per-batch tail, 32 blocks x 1024 threads.
// ============================================================================
__global__ __launch_bounds__(1024) void batch_kernel(
    const float* __restrict__ pooled, const float* __restrict__ maskg,
    const float* __restrict__ pool_w, const float* __restrict__ pool_b,
    const float* __restrict__ pos,
    const float* __restrict__ ln1g, const float* __restrict__ ln1b,
    const float* __restrict__ qkvw, const float* __restrict__ qkvb_g,
    const float* __restrict__ outw, const float* __restrict__ outb,
    const float* __restrict__ ln2g, const float* __restrict__ ln2b,
    const float* __restrict__ ff1w, const float* __restrict__ ff1b,
    const float* __restrict__ ff2w, const float* __restrict__ ff2b,
    const float* __restrict__ flng, const float* __restrict__ flnb,
    const float* __restrict__ ew1, const float* __restrict__ eb1,
    const float* __restrict__ ew2, const float* __restrict__ eb2,
    const float* __restrict__ gfw, const float* __restrict__ gfb,
    const float* __restrict__ gfailw, const float* __restrict__ gfailb,
    const float* __restrict__ failw, const float* __restrict__ failb,
    float* __restrict__ ctxg, float* __restrict__ moefg,
    float* __restrict__ logitsfg, int* __restrict__ tifg,
    float* __restrict__ outg){
  __shared__ float zf[32][128];
  __shared__ float ybuf[32][128];
  __shared__ float qkvb[32][385];
  __shared__ float sc[8][33][33];
  __shared__ float ps[32][64];
  __shared__ float msk[32];
  __shared__ float rin[256];
  __shared__ float meanc[128];
  __shared__ float h1all[4][256];
  __shared__ float oall[4][128];
  __shared__ float lf[16], lfail[16];
  __shared__ int   tisel[4];
  __shared__ float twsel[4];
  __shared__ float moefail[128];
  __shared__ float cntS;

  const int b = blockIdx.x;
  const int tid = threadIdx.x;
  const int lane = tid & 63;

  if (tid < 32) msk[tid] = maskg[b * 32 + tid];
  #pragma unroll
  for (int i = 0; i < 2; ++i){
    int item = tid + 1024 * i;
    int n = item >> 6, c = item & 63;
    ps[n][c] = pooled[(size_t)(b * 32 + n) * 64 + c];
  }
  __syncthreads();

  // z init
  {
    int jb = tid & 63, nb = tid >> 6;
    float acc[2][2];
    #pragma unroll
    for (int nn = 0; nn < 2; ++nn)
      #pragma unroll
      for (int jj = 0; jj < 2; ++jj){
        int d = jb * 2 + jj, n = nb * 2 + nn;
        acc[nn][jj] = pool_b[d] + pos[n * 128 + d];
      }
    #pragma unroll 8
    for (int k = 0; k < 64; ++k){
      float w0 = pool_w[k * 128 + jb * 2], w1 = pool_w[k * 128 + jb * 2 + 1];
      #pragma unroll
      for (int nn = 0; nn < 2; ++nn){
        float y = ps[nb * 2 + nn][k];
        acc[nn][0] += y * w0; acc[nn][1] += y * w1;
      }
    }
    #pragma unroll
    for (int nn = 0; nn < 2; ++nn){
      zf[nb * 2 + nn][jb * 2]     = acc[nn][0];
      zf[nb * 2 + nn][jb * 2 + 1] = acc[nn][1];
    }
  }
  __syncthreads();

  for (int l = 0; l < 2; ++l){
    const float* Wq = qkvw + (size_t)l * 49152;
    const float* bq = qkvb_g + l * 384;
    const float* Wo = outw + (size_t)l * 16384;
    const float* bo = outb + l * 128;
    const float* W1 = ff1w + (size_t)l * 32768;
    const float* bf1 = ff1b + l * 256;
    const float* W2 = ff2w + (size_t)l * 32768;
    const float* bf2 = ff2b + l * 128;
    const float* g1 = ln1g + l * 128; const float* bb1 = ln1b + l * 128;
    const float* g2 = ln2g + l * 128; const float* bb2 = ln2b + l * 128;

    // LN1
    #pragma unroll
    for (int rr = 0; rr < 2; ++rr){
      int row = (tid >> 6) * 2 + rr;
      float x0 = zf[row][lane], x1 = zf[row][lane + 64];
      float mean = waveReduceSum(x0 + x1) * (1.f / 128.f);
      float d0 = x0 - mean, d1 = x1 - mean;
      float var = waveReduceSum(d0 * d0 + d1 * d1) * (1.f / 128.f);
      float rstd = rsqrtf(var + 1e-5f);
      ybuf[row][lane]      = d0 * rstd * g1[lane] + bb1[lane];
      ybuf[row][lane + 64] = d1 * rstd * g1[lane + 64] + bb1[lane + 64];
    }
    __syncthreads();

    // qkv
    {
      int jb = tid & 127, nb = tid >> 7;
      float acc[4][3];
      #pragma unroll
      for (int nn = 0; nn < 4; ++nn)
        #pragma unroll
        for (int jj = 0; jj < 3; ++jj) acc[nn][jj] = 0.f;
      #pragma unroll 8
      for (int k = 0; k < 128; ++k){
        float w0 = Wq[k * 384 + jb * 3], w1 = Wq[k * 384 + jb * 3 + 1], w2v = Wq[k * 384 + jb * 3 + 2];
        #pragma unroll
        for (int nn = 0; nn < 4; ++nn){
          float y = ybuf[nb * 4 + nn][k];
          acc[nn][0] += y * w0; acc[nn][1] += y * w1; acc[nn][2] += y * w2v;
        }
      }
      #pragma unroll
      for (int nn = 0; nn < 4; ++nn)
        #pragma unroll
        for (int jj = 0; jj < 3; ++jj)
          qkvb[nb * 4 + nn][jb * 3 + jj] = acc[nn][jj] + bq[jb * 3 + jj];
    }
    __syncthreads();

    // scores
    #pragma unroll
    for (int i = 0; i < 8; ++i){
      int item = tid + 1024 * i;
      int hh = item >> 10, qi = (item >> 5) & 31, ki = item & 31;
      float a = 0.f;
      #pragma unroll
      for (int d = 0; d < 16; ++d) a += qkvb[qi][hh * 16 + d] * qkvb[ki][128 + hh * 16 + d];
      a *= 0.25f;
      if (msk[ki] == 0.f) a = -1e9f;
      sc[hh][qi][ki] = a;
    }
    __syncthreads();
    // softmax
    {
      int row = tid >> 2, q4 = tid & 3;
      int hh = row >> 5, qi = row & 31;
      float v[8];
      float m = -1e30f;
      #pragma unroll
      for (int j = 0; j < 8; ++j){ v[j] = sc[hh][qi][q4 * 8 + j]; m = fmaxf(m, v[j]); }
      m = fmaxf(m, __shfl_xor(m, 1, 64));
      m = fmaxf(m, __shfl_xor(m, 2, 64));
      float s = 0.f;
      #pragma unroll
      for (int j = 0; j < 8; ++j){ v[j] = expf(v[j] - m); s += v[j]; }
      s += __shfl_xor(s, 1, 64);
      s += __shfl_xor(s, 2, 64);
      float inv = 1.f / s;
      #pragma unroll
      for (int j = 0; j < 8; ++j) sc[hh][qi][q4 * 8 + j] = v[j] * inv;
    }
    __syncthreads();
    // o -> ybuf
    #pragma unroll
    for (int i = 0; i < 4; ++i){
      int item = tid + 1024 * i;
      int n = item >> 7, dd = item & 127, hh = dd >> 4;
      float o = 0.f;
      #pragma unroll
      for (int ki = 0; ki < 32; ++ki) o += sc[hh][n][ki] * qkvb[ki][256 + dd];
      ybuf[n][dd] = o;
    }
    __syncthreads();

    // z += o @ Wo + bo
    {
      int jb = tid & 63, nb = tid >> 6;
      float acc[2][2];
      #pragma unroll
      for (int nn = 0; nn < 2; ++nn){ acc[nn][0] = 0.f; acc[nn][1] = 0.f; }
      #pragma unroll 8
      for (int k = 0; k < 128; ++k){
        float w0 = Wo[k * 128 + jb * 2], w1 = Wo[k * 128 + jb * 2 + 1];
        #pragma unroll
        for (int nn = 0; nn < 2; ++nn){
          float y = ybuf[nb * 2 + nn][k];
          acc[nn][0] += y * w0; acc[nn][1] += y * w1;
        }
      }
      #pragma unroll
      for (int nn = 0; nn < 2; ++nn){
        zf[nb * 2 + nn][jb * 2]     += acc[nn][0] + bo[jb * 2];
        zf[nb * 2 + nn][jb * 2 + 1] += acc[nn][1] + bo[jb * 2 + 1];
      }
    }
    __syncthreads();

    // LN2
    #pragma unroll
    for (int rr = 0; rr < 2; ++rr){
      int row = (tid >> 6) * 2 + rr;
      float x0 = zf[row][lane], x1 = zf[row][lane + 64];
      float mean = waveReduceSum(x0 + x1) * (1.f / 128.f);
      float d0 = x0 - mean, d1 = x1 - mean;
      float var = waveReduceSum(d0 * d0 + d1 * d1) * (1.f / 128.f);
      float rstd = rsqrtf(var + 1e-5f);
      ybuf[row][lane]      = d0 * rstd * g2[lane] + bb2[lane];
      ybuf[row][lane + 64] = d1 * rstd * g2[lane + 64] + bb2[lane + 64];
    }
    __syncthreads();

    // ff1
    {
      int jb = tid & 127, nb = tid >> 7;
      float acc[4][2];
      #pragma unroll
      for (int nn = 0; nn < 4; ++nn){ acc[nn][0] = 0.f; acc[nn][1] = 0.f; }
      #pragma unroll 8
      for (int k = 0; k < 128; ++k){
        float w0 = W1[k * 256 + jb * 2], w1 = W1[k * 256 + jb * 2 + 1];
        #pragma unroll
        for (int nn = 0; nn < 4; ++nn){
          float y = ybuf[nb * 4 + nn][k];
          acc[nn][0] += y * w0; acc[nn][1] += y * w1;
        }
      }
      #pragma unroll
      for (int nn = 0; nn < 4; ++nn){
        qkvb[nb * 4 + nn][jb * 2]     = fmaxf(acc[nn][0] + bf1[jb * 2], 0.f);
        qkvb[nb * 4 + nn][jb * 2 + 1] = fmaxf(acc[nn][1] + bf1[jb * 2 + 1], 0.f);
      }
    }
    __syncthreads();

    // z += ff @ W2 + bf2
    {
      int jb = tid & 63, nb = tid >> 6;
      float acc[2][2];
      #pragma unroll
      for (int nn = 0; nn < 2; ++nn){ acc[nn][0] = 0.f; acc[nn][1] = 0.f; }
      #pragma unroll 8
      for (int k = 0; k < 256; ++k){
        float w0 = W2[k * 128 + jb * 2], w1 = W2[k * 128 + jb * 2 + 1];
        #pragma unroll
        for (int nn = 0; nn < 2; ++nn){
          float y = qkvb[nb * 2 + nn][k];
          acc[nn][0] += y * w0; acc[nn][1] += y * w1;
        }
      }
      #pragma unroll
      for (int nn = 0; nn < 2; ++nn){
        zf[nb * 2 + nn][jb * 2]     += acc[nn][0] + bf2[jb * 2];
        zf[nb * 2 + nn][jb * 2 + 1] += acc[nn][1] + bf2[jb * 2 + 1];
      }
    }
    __syncthreads();
  }

  // final LN * mask -> ybuf + ctx
  #pragma unroll
  for (int rr = 0; rr < 2; ++rr){
    int row = (tid >> 6) * 2 + rr;
    float x0 = zf[row][lane], x1 = zf[row][lane + 64];
    float mean = waveReduceSum(x0 + x1) * (1.f / 128.f);
    float d0 = x0 - mean, d1 = x1 - mean;
    float var = waveReduceSum(d0 * d0 + d1 * d1) * (1.f / 128.f);
    float rstd = rsqrtf(var + 1e-5f);
    float mk = msk[row];
    ybuf[row][lane]      = (d0 * rstd * flng[lane] + flnb[lane]) * mk;
    ybuf[row][lane + 64] = (d1 * rstd * flng[lane + 64] + flnb[lane + 64]) * mk;
  }
  if (tid == 0){
    float c = 0.f;
    for (int n = 0; n < 32; ++n) c += maskg[b * 32 + n];
    cntS = fmaxf(c, 1.f);
  }
  __syncthreads();
  #pragma unroll
  for (int i = 0; i < 4; ++i){
    int item = tid + 1024 * i;
    int n = item >> 7, d = item & 127;
    ctxg[(size_t)(b * 32 + n) * 128 + d] = ybuf[n][d];
  }
  if (tid < 128){
    float s = 0.f, s2 = 0.f;
    #pragma unroll 8
    for (int n = 0; n < 32; ++n){ float v = ybuf[n][tid]; s += v; s2 += v * v; }
    float mean = s / cntS;
    float var = s2 / cntS - mean * mean;
    meanc[tid] = mean;
    rin[tid] = mean;
    rin[128 + tid] = sqrtf(fmaxf(var, 1e-6f));
  }
  __syncthreads();
  // gates
  {
    int g = tid >> 9;
    int e = (tid >> 5) & 15, kk = tid & 31;
    const float* gw = g ? gfailw : gfw;
    float a = 0.f;
    #pragma unroll
    for (int j = 0; j < 8; ++j){
      int k = kk * 8 + j;
      a += rin[k] * gw[k * 16 + e];
    }
    a += __shfl_xor(a, 1, 64);  a += __shfl_xor(a, 2, 64);
    a += __shfl_xor(a, 4, 64);  a += __shfl_xor(a, 8, 64);
    a += __shfl_xor(a, 16, 64);
    if (kk == 0){
      if (g == 0){
        float r = a + gfb[e];
        lf[e] = r;
        logitsfg[b * 16 + e] = r;
      } else {
        lfail[e] = a + gfailb[e];
      }
    }
  }
  __syncthreads();
  if (tid < 2){
    const float* lg = (tid == 0) ? lf : lfail;
    int i0 = 0; float v0 = lg[0];
    for (int e = 1; e < 16; ++e) if (lg[e] > v0){ v0 = lg[e]; i0 = e; }
    int i1 = -1; float v1 = -1e30f;
    for (int e = 0; e < 16; ++e) if (e != i0 && lg[e] > v1){ v1 = lg[e]; i1 = e; }
    float e1 = expf(v1 - v0);
    float den = 1.f / (1.f + e1);
    tisel[tid * 2] = i0; tisel[tid * 2 + 1] = i1;
    twsel[tid * 2] = den; twsel[tid * 2 + 1] = e1 * den;
    if (tid == 0){ tifg[b * 2] = i0; tifg[b * 2 + 1] = i1; }
  }
  __syncthreads();
  // MoE: 4 selected experts in parallel
  {
    int sel = tid >> 8, h = tid & 255;
    int e = tisel[sel];
    float a = eb1[e * 256 + h];
    #pragma unroll 8
    for (int k = 0; k < 128; ++k) a += meanc[k] * ew1[(size_t)(e * 128 + k) * 256 + h];
    h1all[sel][h] = fmaxf(a, 0.f);
  }
  __syncthreads();
  if (tid < 512){
    int sel = tid >> 7, d = tid & 127;
    int e = tisel[sel];
    float o = eb2[e * 128 + d];
    #pragma unroll 8
    for (int k = 0; k < 256; ++k) o += h1all[sel][k] * ew2[(size_t)(e * 256 + k) * 128 + d];
    oall[sel][d] = twsel[sel] * o;
  }
  __syncthreads();
  if (tid < 128){
    moefg[b * 128 + tid] = oall[0][tid] + oall[1][tid];
    moefail[tid] = oall[2][tid] + oall[3][tid];
  }
  __syncthreads();
  if (tid < 3){
    float a = failb[tid];
    for (int k = 0; k < 128; ++k) a += moefail[k] * failw[k * 3 + tid];
    outg[3072 + b * 3 + tid] = a;
  }
}

// ---------------- gate (rca) ----------------
__global__ void gate_kernel(const float* __restrict__ gin, const float* __restrict__ gw,
                            const float* __restrict__ gb, int ntok, int K,
                            int* __restrict__ ti, float* __restrict__ tw,
                            float* __restrict__ logits_out){
  int tok = blockIdx.x * 64 + threadIdx.x;
  if (tok >= ntok) return;
  float acc[16];
  #pragma unroll
  for (int e = 0; e < 16; ++e) acc[e] = gb[e];
  const float* gr = gin + (size_t)tok * K;
  #pragma unroll 4
  for (int k = 0; k < K; ++k){
    float gv = gr[k];
    #pragma unroll
    for (int e = 0; e < 16; ++e) acc[e] = fmaf(gv, gw[k*16 + e], acc[e]);
  }
  if (logits_out){
    #pragma unroll
    for (int e = 0; e < 16; ++e) logits_out[tok*16 + e] = acc[e];
  }
  int i0 = 0; float v0 = acc[0];
  #pragma unroll
  for (int e = 1; e < 16; ++e) if (acc[e] > v0){ v0 = acc[e]; i0 = e; }
  int i1 = -1; float v1 = -1e30f;
  #pragma unroll
  for (int e = 0; e < 16; ++e) if (e != i0 && acc[e] > v1){ v1 = acc[e]; i1 = e; }
  float e1 = expf(v1 - v0);
  float den = 1.f / (1.f + e1);
  ti[tok*2] = i0; ti[tok*2+1] = i1;
  tw[tok*2] = den; tw[tok*2+1] = e1 * den;
}

// ---------------- MoE expert eval (rca) ----------------
__global__ void moe_expert_kernel(const float* __restrict__ xin, const int* __restrict__ ti,
                                  const float* __restrict__ tw,
                                  const float* __restrict__ w1, const float* __restrict__ b1,
                                  const float* __restrict__ w2, const float* __restrict__ b2,
                                  const float* __restrict__ mask, float* __restrict__ yout){
  int tok = blockIdx.x;
  int tid = threadIdx.x; // 256
  __shared__ float xs[128];
  __shared__ float h1[256];
  if (tid < 128) xs[tid] = xin[(size_t)tok*128 + tid];
  __syncthreads();
  float accv = 0.f;
  for (int kkk = 0; kkk < 2; ++kkk){
    int e = ti[tok*2 + kkk];
    float wv = tw[tok*2 + kkk];
    float a = b1[e*256 + tid];
    #pragma unroll 8
    for (int k = 0; k < 128; ++k) a = fmaf(xs[k], w1[(size_t)(e*128 + k)*256 + tid], a);
    __syncthreads();
    h1[tid] = fmaxf(a, 0.f);
    __syncthreads();
    if (tid < 128){
      float o = b2[e*128 + tid];
      #pragma unroll 8
      for (int k = 0; k < 256; ++k) o = fmaf(h1[k], w2[(size_t)(e*256 + k)*128 + tid], o);
      accv += wv * o;
    }
  }
  if (tid < 128){
    if (mask) accv *= mask[tok];
    yout[(size_t)tok*128 + tid] = accv;
  }
}

// ---------------- aux loss ----------------
__global__ void aux_kernel(const float* __restrict__ logits, const int* __restrict__ ti,
                           float* __restrict__ out_scalar){
  if (threadIdx.x != 0 || blockIdx.x != 0) return;
  float pm[16];
  for (int e = 0; e < 16; ++e) pm[e] = 0.f;
  for (int i = 0; i < 32; ++i){
    const float* row = logits + i*16;
    float m = -1e30f;
    for (int e = 0; e < 16; ++e) m = fmaxf(m, row[e]);
    float s = 0.f;
    float ex[16];
    for (int e = 0; e < 16; ++e){ ex[e] = expf(row[e] - m); s += ex[e]; }
    for (int e = 0; e < 16; ++e) pm[e] += ex[e] / s;
  }
  float cnt[16];
  for (int e = 0; e < 16; ++e) cnt[e] = 0.f;
  for (int i = 0; i < 64; ++i) cnt[ti[i]] += 1.f;
  float loss = 0.f;
  for (int e = 0; e < 16; ++e) loss += (pm[e] / 32.f) * (cnt[e] / 64.f);
  out_scalar[0] = 16.f * loss;
}

// ---------------- pred + rca heads ----------------
__global__ void heads_kernel(const float* __restrict__ st_last, const float* __restrict__ ctx,
                             const float* __restrict__ moe_f, const float* __restrict__ moe_rca,
                             const float* __restrict__ pred_w, const float* __restrict__ pred_b,
                             const float* __restrict__ rca_w, const float* __restrict__ rca_b,
                             float* __restrict__ out){
  int bn = blockIdx.x * 256 + threadIdx.x;
  if (bn >= 1024) return;
  int b = bn >> 5;
  float p0 = pred_b[0], p1 = pred_b[1], p2 = pred_b[2];
  float r = rca_b[0];
  #pragma unroll 4
  for (int i = 0; i < 64; ++i){
    float v = st_last[(size_t)bn*64 + i];
    p0 = fmaf(v, pred_w[i*3+0], p0); p1 = fmaf(v, pred_w[i*3+1], p1); p2 = fmaf(v, pred_w[i*3+2], p2);
    r = fmaf(v, rca_w[i], r);
  }
  #pragma unroll 4
  for (int i = 0; i < 128; ++i){
    float v = ctx[(size_t)bn*128 + i];
    int ii = 64 + i;
    p0 = fmaf(v, pred_w[ii*3+0], p0); p1 = fmaf(v, pred_w[ii*3+1], p1); p2 = fmaf(v, pred_w[ii*3+2], p2);
    r = fmaf(v, rca_w[ii], r);
  }
  #pragma unroll 4
  for (int i = 0; i < 128; ++i){
    int ii = 192 + i;
    float vp = moe_f[(size_t)b*128 + i];
    p0 = fmaf(vp, pred_w[ii*3+0], p0); p1 = fmaf(vp, pred_w[ii*3+1], p1); p2 = fmaf(vp, pred_w[ii*3+2], p2);
    float vr = moe_rca[(size_t)bn*128 + i];
    r = fmaf(vr, rca_w[ii], r);
  }
  out[bn*3+0] = p0; out[bn*3+1] = p1; out[bn*3+2] = p2;
  out[3168 + bn] = r;
}

// ================= host =================
extern "C" void kernel_launch(void* const* d_in, const int* in_sizes, int n_in,
                              void* d_out, int out_size, void* d_ws, size_t ws_size,
                              hipStream_t stream){
  const float* x        = (const float*)d_in[0];
  const float* mask     = (const float*)d_in[1];
  const float* proj_w   = (const float*)d_in[2];
  const float* proj_b   = (const float*)d_in[3];
  const float* tcn_w1   = (const float*)d_in[4];
  const float* tcn_b1   = (const float*)d_in[5];
  const float* tcn_w2   = (const float*)d_in[6];
  const float* tcn_b2   = (const float*)d_in[7];
  const float* tcn_ln_g = (const float*)d_in[8];
  const float* tcn_ln_b = (const float*)d_in[9];
  const float* pool_w   = (const float*)d_in[10];
  const float* pool_b   = (const float*)d_in[11];
  const float* pos_inter= (const float*)d_in[12];
  const float* tx_ln1_g = (const float*)d_in[13];
  const float* tx_ln1_b = (const float*)d_in[14];
  const float* tx_qkv_w = (const float*)d_in[15];
  const float* tx_qkv_b = (const float*)d_in[16];
  const float* tx_out_w = (const float*)d_in[17];
  const float* tx_out_b = (const float*)d_in[18];
  const float* tx_ln2_g = (const float*)d_in[19];
  const float* tx_ln2_b = (const float*)d_in[20];
  const float* tx_ff1_w = (const float*)d_in[21];
  const float* tx_ff1_b = (const float*)d_in[22];
  const float* tx_ff2_w = (const float*)d_in[23];
  const float* tx_ff2_b = (const float*)d_in[24];
  const float* tx_fln_g = (const float*)d_in[25];
  const float* tx_fln_b = (const float*)d_in[26];
  const float* exp_w1   = (const float*)d_in[27];
  const float* exp_b1   = (const float*)d_in[28];
  const float* exp_w2   = (const float*)d_in[29];
  const float* exp_b2   = (const float*)d_in[30];
  const float* gate_f_w = (const float*)d_in[31];
  const float* gate_f_b = (const float*)d_in[32];
  const float* gate_fail_w = (const float*)d_in[33];
  const float* gate_fail_b = (const float*)d_in[34];
  const float* gate_rca_w  = (const float*)d_in[35];
  const float* gate_rca_b  = (const float*)d_in[36];
  const float* pred_w   = (const float*)d_in[37];
  const float* pred_b   = (const float*)d_in[38];
  const float* fail_w   = (const float*)d_in[39];
  const float* fail_b   = (const float*)d_in[40];
  const float* rca_w    = (const float*)d_in[41];
  const float* rca_b    = (const float*)d_in[42];
  float* out = (float*)d_out;
  float* W = (float*)d_ws;

  // ---- workspace layout (float offsets); total ~2.5 MB ----
  const size_t o_pooled  = 0;          // 1024*64
  const size_t o_stlast  = 65536;      // 1024*64
  const size_t o_ctx     = 131072;     // 1024*128
  const size_t o_moef    = 262144;     // 32*128
  const size_t o_moerca  = 266240;     // 1024*128
  const size_t o_logitsf = 397312;     // 32*16
  const size_t o_tif     = 397824;     // 64 ints
  const size_t o_twrca   = 397888;     // 2048
  const size_t o_tirca   = 399936;     // 2048 ints
  const size_t o_petab   = 401984;     // 512*64
  unsigned short* wfragU = (unsigned short*)(W + 434752);   // 786432 B

  // 1. weight fragments + PE table
  init_kernel<<<512, 256, 0, stream>>>(tcn_w1, tcn_w2, wfragU, W + o_petab);

  // 2. persistent per-sequence TCN (proj + 4 layers + LN/pool, all in LDS)
  tcn_persist_kernel<<<1024, 512, 0, stream>>>(
      x, wfragU, tcn_b1, tcn_b2, W + o_petab, proj_w, proj_b,
      tcn_ln_g, tcn_ln_b, mask, W + o_pooled, W + o_stlast);

  // 3. fused tail
  batch_kernel<<<32, 1024, 0, stream>>>(
      W + o_pooled, mask, pool_w, pool_b, pos_inter,
      tx_ln1_g, tx_ln1_b, tx_qkv_w, tx_qkv_b, tx_out_w, tx_out_b,
      tx_ln2_g, tx_ln2_b, tx_ff1_w, tx_ff1_b, tx_ff2_w, tx_ff2_b,
      tx_fln_g, tx_fln_b,
      exp_w1, exp_b1, exp_w2, exp_b2,
      gate_f_w, gate_f_b, gate_fail_w, gate_fail_b, fail_w, fail_b,
      W + o_ctx, W + o_moef, W + o_logitsf, (int*)(W + o_tif), out);

  // 4. rca path
  gate_kernel<<<16, 64, 0, stream>>>(W + o_ctx, gate_rca_w, gate_rca_b, 1024, 128,
                                     (int*)(W + o_tirca), W + o_twrca, nullptr);
  moe_expert_kernel<<<1024, 256, 0, stream>>>(W + o_ctx, (int*)(W + o_tirca), W + o_twrca,
                                              exp_w1, exp_b1, exp_w2, exp_b2, mask, W + o_moerca);

  // 5. aux + heads
  aux_kernel<<<1, 64, 0, stream>>>(W + o_logitsf, (int*)(W + o_tif), out + 4192);
  heads_kernel<<<4, 256, 0, stream>>>(W + o_stlast, W + o_ctx, W + o_moef, W + o_moerca,
                                      pred_w, pred_b, rca_w, rca_b, out);
}